// Round 1
// baseline (3352.889 us; speedup 1.0000x reference)
//
#include <hip/hip_runtime.h>
#include <hip/hip_bf16.h>
#include <math.h>

// Problem constants
#define BROWS 8192
#define SDIM  512
#define HDIM  512
#define KKNOT 8
#define NCOL  (SDIM * (2 * KKNOT + 1))   // 8704
#define EPSK  1e-6f

// ---------------------------------------------------------------------------
// Kernel 1: hid = tanh((x_a - 0.5) @ W1 + b1)    (8192x512) @ (512x512)
// 64x64 tile, BK=16, 256 threads, 4x4 per thread, fp32.
// ---------------------------------------------------------------------------
__global__ __launch_bounds__(256) void gemm1_tanh(
    const float* __restrict__ x,      // (B, 2S) row-major; x_a = cols [0,512)
    const float* __restrict__ W1,     // (S, H) row-major
    const float* __restrict__ b1,     // (H,)
    float* __restrict__ hid)          // (B, H)
{
    __shared__ float As[16][68];      // As[k][m], pad 68 (272B, 16B-aligned rows)
    __shared__ float Bs[16][68];      // Bs[k][n]

    const int bm = blockIdx.y * 64;
    const int bn = blockIdx.x * 64;
    const int tid = threadIdx.x;
    const int tm = (tid >> 4) * 4;    // 0..60
    const int tn = (tid & 15) * 4;    // 0..60
    // staging assignments
    const int ar = tid >> 2;          // 0..63 (row of A tile)
    const int ac = (tid & 3) * 4;     // 0,4,8,12 (col of A tile)
    const int bk = tid >> 4;          // 0..15 (row of B tile)
    const int bn4 = (tid & 15) * 4;   // 0..60

    float acc[4][4];
#pragma unroll
    for (int i = 0; i < 4; i++)
#pragma unroll
        for (int j = 0; j < 4; j++) acc[i][j] = 0.f;

    for (int k0 = 0; k0 < SDIM; k0 += 16) {
        float4 av = *(const float4*)&x[(size_t)(bm + ar) * (2 * SDIM) + k0 + ac];
        float4 bv = *(const float4*)&W1[(size_t)(k0 + bk) * HDIM + bn + bn4];
        __syncthreads();
        As[ac + 0][ar] = av.x - 0.5f;
        As[ac + 1][ar] = av.y - 0.5f;
        As[ac + 2][ar] = av.z - 0.5f;
        As[ac + 3][ar] = av.w - 0.5f;
        *(float4*)&Bs[bk][bn4] = bv;
        __syncthreads();
#pragma unroll
        for (int k = 0; k < 16; k++) {
            float4 a = *(const float4*)&As[k][tm];
            float4 b = *(const float4*)&Bs[k][tn];
            acc[0][0] += a.x * b.x; acc[0][1] += a.x * b.y; acc[0][2] += a.x * b.z; acc[0][3] += a.x * b.w;
            acc[1][0] += a.y * b.x; acc[1][1] += a.y * b.y; acc[1][2] += a.y * b.z; acc[1][3] += a.y * b.w;
            acc[2][0] += a.z * b.x; acc[2][1] += a.z * b.y; acc[2][2] += a.z * b.z; acc[2][3] += a.z * b.w;
            acc[3][0] += a.w * b.x; acc[3][1] += a.w * b.y; acc[3][2] += a.w * b.z; acc[3][3] += a.w * b.w;
        }
    }
    float4 bias = *(const float4*)&b1[bn + tn];
    const float bb[4] = {bias.x, bias.y, bias.z, bias.w};
#pragma unroll
    for (int i = 0; i < 4; i++) {
        float4 o;
        o.x = tanhf(acc[i][0] + bb[0]);
        o.y = tanhf(acc[i][1] + bb[1]);
        o.z = tanhf(acc[i][2] + bb[2]);
        o.w = tanhf(acc[i][3] + bb[3]);
        *(float4*)&hid[(size_t)(bm + tm + i) * HDIM + bn + tn] = o;
    }
}

// ---------------------------------------------------------------------------
// Kernel 2: fused GEMM2 + spline epilogue.
// net[b,s,0:17] = tanh(hid[b,:] @ W2[:, s*17:(s+1)*17] + b2)
// Block: 128 rows x 8 splines. 256 threads; thread = (rg 0..31, sp 0..7),
// owns 4 rows x 1 spline -> acc[4][17]. BK=16.
// Epilogue: softmax(w_raw), trapezoid-normalized h, knot search, phi_b,
// per-row sum of log terms (shfl-reduced over the 8 sp lanes, atomicAdd).
// ---------------------------------------------------------------------------
__global__ __launch_bounds__(256) void gemm2_spline(
    const float* __restrict__ hid,    // (B, H)
    const float* __restrict__ W2,     // (H, 8704)
    const float* __restrict__ b2,     // (8704,)
    const float* __restrict__ x,      // (B, 2S); x_b = cols [512,1024)
    float* __restrict__ out,          // (B*1024 + B)
    float* __restrict__ logacc)       // (B,) pre-zeroed
{
    __shared__ float hidS[16][132];       // hidS[k][row], stride 132 (16B-aligned)
    __shared__ float w2S[16][8][20];      // w2S[k][spline][c], stride 20 (16B-aligned)

    const int sp = threadIdx.x & 7;       // spline within block
    const int rg = threadIdx.x >> 3;      // 0..31 row group (4 rows each)
    const int rowbase = blockIdx.y * 128;
    const int spbase = blockIdx.x * 8;
    const int colbase = spbase * 17;      // 136 contiguous W2 columns

    // staging assignment for hid tile: 128 rows x 16 cols
    const int lr = threadIdx.x >> 1;      // 0..127
    const int lh = threadIdx.x & 1;       // col half (8 cols each)

    float acc[4][17];
#pragma unroll
    for (int i = 0; i < 4; i++)
#pragma unroll
        for (int c = 0; c < 17; c++) acc[i][c] = 0.f;

    for (int k0 = 0; k0 < HDIM; k0 += 16) {
        // Preload globals to registers
        const float* hp = &hid[(size_t)(rowbase + lr) * HDIM + k0 + lh * 8];
        float4 v0 = *(const float4*)hp;
        float4 v1 = *(const float4*)(hp + 4);
        float wtmp[9];
        int nw = 0;
        for (int idx = threadIdx.x; idx < 16 * 136; idx += 256)
            wtmp[nw++] = W2[(size_t)(k0 + (idx / 136)) * NCOL + colbase + (idx % 136)];
        __syncthreads();   // previous iteration's reads done
        hidS[lh * 8 + 0][lr] = v0.x;
        hidS[lh * 8 + 1][lr] = v0.y;
        hidS[lh * 8 + 2][lr] = v0.z;
        hidS[lh * 8 + 3][lr] = v0.w;
        hidS[lh * 8 + 4][lr] = v1.x;
        hidS[lh * 8 + 5][lr] = v1.y;
        hidS[lh * 8 + 6][lr] = v1.z;
        hidS[lh * 8 + 7][lr] = v1.w;
        nw = 0;
        for (int idx = threadIdx.x; idx < 16 * 136; idx += 256) {
            int kk = idx / 136;
            int cc = idx - kk * 136;
            int ss = cc / 17;
            int c2 = cc - ss * 17;
            w2S[kk][ss][c2] = wtmp[nw++];
        }
        __syncthreads();
#pragma unroll
        for (int k = 0; k < 16; k++) {
            float4 a = *(const float4*)&hidS[k][rg * 4];
#pragma unroll
            for (int c = 0; c < 17; c += 4) {       // 4x float4 + 1 scalar
                if (c < 16) {
                    float4 w4 = *(const float4*)&w2S[k][sp][c];
                    acc[0][c + 0] += a.x * w4.x; acc[1][c + 0] += a.y * w4.x; acc[2][c + 0] += a.z * w4.x; acc[3][c + 0] += a.w * w4.x;
                    acc[0][c + 1] += a.x * w4.y; acc[1][c + 1] += a.y * w4.y; acc[2][c + 1] += a.z * w4.y; acc[3][c + 1] += a.w * w4.y;
                    acc[0][c + 2] += a.x * w4.z; acc[1][c + 2] += a.y * w4.z; acc[2][c + 2] += a.z * w4.z; acc[3][c + 2] += a.w * w4.z;
                    acc[0][c + 3] += a.x * w4.w; acc[1][c + 3] += a.y * w4.w; acc[2][c + 3] += a.z * w4.w; acc[3][c + 3] += a.w * w4.w;
                } else {
                    float w = w2S[k][sp][16];
                    acc[0][16] += a.x * w; acc[1][16] += a.y * w; acc[2][16] += a.z * w; acc[3][16] += a.w * w;
                }
            }
        }
    }

    // ---- epilogue ----
    const int sglob = spbase + sp;
    float b2v[17];
#pragma unroll
    for (int c = 0; c < 17; c++) b2v[c] = b2[colbase + sp * 17 + c];

#pragma unroll
    for (int i = 0; i < 4; i++) {
        const int row = rowbase + rg * 4 + i;
        float net[17];
#pragma unroll
        for (int c = 0; c < 17; c++) net[c] = tanhf(acc[i][c] + b2v[c]);

        // softmax over net[9..16]
        float m = net[9];
#pragma unroll
        for (int c = 10; c < 17; c++) m = fmaxf(m, net[c]);
        float e[8], se = 0.f;
#pragma unroll
        for (int c = 0; c < 8; c++) { e[c] = expf(net[9 + c] - m); se += e[c]; }
        const float inv_se = 1.f / se;
        float wn[8];
#pragma unroll
        for (int c = 0; c < 8; c++) wn[c] = e[c] * inv_se;

        float eh[9];
#pragma unroll
        for (int j = 0; j < 9; j++) eh[j] = expf(net[j]);
        float denom = 0.f;
#pragma unroll
        for (int c = 0; c < 8; c++) denom += 0.5f * wn[c] * (eh[c] + eh[c + 1]);
        const float invden = 1.f / denom;
        float hn[9];
#pragma unroll
        for (int j = 0; j < 9; j++) hn[j] = eh[j] * invden;

        const float xb = x[(size_t)row * (2 * SDIM) + SDIM + sglob];

        // knot scan: k = last c in [0,8) with x_knots[c] < xb  (x_knots[0] = -eps
        // is always < xb since xb >= 0), matching clip(count-1, 0, K-1).
        float xk = -EPSK, pk = 0.f;
        float selw = wn[0], selh = hn[0], selh1 = hn[1], selx = xk, selp = pk;
#pragma unroll
        for (int c = 0; c < 8; c++) {
            const bool t = (xk < xb);
            selw = t ? wn[c] : selw;
            selh = t ? hn[c] : selh;
            selh1 = t ? hn[c + 1] : selh1;
            selx = t ? xk : selx;
            selp = t ? pk : selp;
            xk += wn[c];
            pk += 0.5f * wn[c] * (hn[c] + hn[c + 1]);
        }
        const float alpha = (xb - selx) / selw;
        const float phib = selp + alpha * selh * selw
                         + 0.5f * alpha * alpha * (selh1 - selh) * selw;
        out[(size_t)row * (2 * SDIM) + SDIM + sglob] = phib;

        float lg = logf(selh + alpha * (selh1 - selh));
        // reduce across the 8 spline lanes (tid bits 0..2 within the wave)
        lg += __shfl_xor(lg, 1);
        lg += __shfl_xor(lg, 2);
        lg += __shfl_xor(lg, 4);
        if (sp == 0) atomicAdd(&logacc[row], lg);
    }
}

// ---------------------------------------------------------------------------
// Kernel 3: copy x_a into out[:, :512]; new_log_density = log_density - logacc
// ---------------------------------------------------------------------------
__global__ __launch_bounds__(256) void finalize_k(
    const float* __restrict__ x,
    const float* __restrict__ logd,
    const float* __restrict__ logacc,
    float* __restrict__ out)
{
    const int t = blockIdx.x * 256 + threadIdx.x;   // 8192*128 threads
    const int b = t >> 7;
    const int j = (t & 127) * 4;
    float4 v = *(const float4*)&x[(size_t)b * (2 * SDIM) + j];
    *(float4*)&out[(size_t)b * (2 * SDIM) + j] = v;
    if ((t & 127) == 0)
        out[(size_t)BROWS * (2 * SDIM) + b] = logd[b] - logacc[b];
}

// ---------------------------------------------------------------------------
extern "C" void kernel_launch(void* const* d_in, const int* in_sizes, int n_in,
                              void* d_out, int out_size, void* d_ws, size_t ws_size,
                              hipStream_t stream) {
    const float* x    = (const float*)d_in[0];
    const float* logd = (const float*)d_in[1];
    const float* W1   = (const float*)d_in[2];
    const float* b1   = (const float*)d_in[3];
    const float* W2   = (const float*)d_in[4];
    const float* b2   = (const float*)d_in[5];
    float* out = (float*)d_out;

    float* logacc = (float*)d_ws;             // 8192 floats
    float* hid    = logacc + BROWS;           // 8192*512 floats

    hipMemsetAsync(d_ws, 0, BROWS * sizeof(float), stream);

    gemm1_tanh<<<dim3(HDIM / 64, BROWS / 64), 256, 0, stream>>>(x, W1, b1, hid);
    gemm2_spline<<<dim3(SDIM / 8, BROWS / 128), 256, 0, stream>>>(hid, W2, b2, x, out, logacc);
    finalize_k<<<(BROWS * 128) / 256, 256, 0, stream>>>(x, logd, logacc, out);
}

// Round 2
// 377.221 us; speedup vs baseline: 8.8884x; 8.8884x over previous
//
#include <hip/hip_runtime.h>
#include <stdint.h>
#include <math.h>

// Problem constants
#define BROWS 8192
#define SDIM  512
#define HDIM  512
#define NCOL  8704          // S*(2K+1)
#define EPSK  1e-6f

typedef __attribute__((ext_vector_type(8))) short bf16x8;   // MFMA A/B frag (4 VGPR)
typedef __attribute__((ext_vector_type(4))) short bf16x4;
typedef __attribute__((ext_vector_type(4))) float f32x4;    // MFMA C/D frag

__device__ __forceinline__ unsigned short f2bf(float f) {   // RTNE f32->bf16
    unsigned u = __float_as_uint(f);
    u += 0x7fffu + ((u >> 16) & 1u);
    return (unsigned short)(u >> 16);
}
__device__ __forceinline__ float bf2f(unsigned short s) {
    return __uint_as_float(((unsigned)s) << 16);
}

// async global->LDS, 16B per lane; LDS dst must be wave-uniform (lane*16 appended by HW)
#define GLD16(g, l)                                                         \
    __builtin_amdgcn_global_load_lds(                                       \
        (const __attribute__((address_space(1))) void*)(g),                 \
        (__attribute__((address_space(3))) void*)(l), 16, 0, 0)

// ---------------------------------------------------------------------------
// Prep: out[C][R] (bf16) = transpose of in[R][C] (f32). 32x32 LDS tiles.
// ---------------------------------------------------------------------------
__global__ __launch_bounds__(256) void transpose_to_bf16(
    const float* __restrict__ in, unsigned short* __restrict__ out,
    int R, int C)
{
    __shared__ float tile[32 * 33];
    const int cb = blockIdx.x * 32;
    const int rb = blockIdx.y * 32;
    const int t  = threadIdx.x;
    const int ty = t >> 3, tx = (t & 7) * 4;
    float4 v = *(const float4*)&in[(size_t)(rb + ty) * C + cb + tx];
    tile[ty * 33 + tx + 0] = v.x;
    tile[ty * 33 + tx + 1] = v.y;
    tile[ty * 33 + tx + 2] = v.z;
    tile[ty * 33 + tx + 3] = v.w;
    __syncthreads();
    const int oy = t >> 3, ox = (t & 7) * 4;
    bf16x4 o;
    o[0] = (short)f2bf(tile[(ox + 0) * 33 + oy]);
    o[1] = (short)f2bf(tile[(ox + 1) * 33 + oy]);
    o[2] = (short)f2bf(tile[(ox + 2) * 33 + oy]);
    o[3] = (short)f2bf(tile[(ox + 3) * 33 + oy]);
    *(bf16x4*)&out[(size_t)(cb + oy) * R + rb + ox] = o;
}

// ---------------------------------------------------------------------------
// GEMM1 (MFMA): hid = bf16(tanh((x_a-0.5) @ W1 + b1))
// 128x128 tile, BK=32, 4 waves (2x2), each 64x64 = 16 MFMA tiles.
// A staged via VGPR (fp32->bf16 convert on the fly), B via global_load_lds.
// ---------------------------------------------------------------------------
__global__ __launch_bounds__(256) void gemm1_mfma(
    const float* __restrict__ x,
    const unsigned short* __restrict__ W1T,   // (H,S) bf16 k-contiguous
    const float* __restrict__ b1,
    unsigned short* __restrict__ hid)         // (B,H) bf16
{
    __shared__ short As[128 * 32];
    __shared__ short Bs[128 * 32];
    const int bm   = blockIdx.y * 128;
    const int bn   = blockIdx.x * 128;
    const int tid  = threadIdx.x;
    const int lane = tid & 63;
    const int wave = tid >> 6;
    const int ln15 = lane & 15;
    const int quad = lane >> 4;
    const int wm   = (wave >> 1) * 64;
    const int wn   = (wave & 1) * 64;
    // A staging: thread -> (row, 16-elem half)
    const int arow = tid >> 1, ahalf = tid & 1;
    // B staging: lane -> (row-in-chunk, 8-elem sub)
    const int brow = lane >> 2, bsub = lane & 3;

    f32x4 acc[4][4];
#pragma unroll
    for (int i = 0; i < 4; i++)
#pragma unroll
        for (int j = 0; j < 4; j++) acc[i][j] = (f32x4){0.f, 0.f, 0.f, 0.f};

    for (int k0 = 0; k0 < SDIM; k0 += 32) {
        // prefetch A floats to VGPR before the barrier
        const float4* xq = (const float4*)&x[(size_t)(bm + arow) * (2 * SDIM) + k0 + ahalf * 16];
        float4 f0 = xq[0], f1 = xq[1], f2 = xq[2], f3 = xq[3];
        __syncthreads();
#pragma unroll
        for (int c = 0; c < 2; c++) {
            const int chunk = wave * 2 + c;   // 0..7 -> rows chunk*16..+16
            GLD16(&W1T[(size_t)(bn + chunk * 16 + brow) * SDIM + k0 + bsub * 8],
                  &Bs[chunk * 512]);
        }
        bf16x8 v0, v1;
        v0[0] = (short)f2bf(f0.x - 0.5f); v0[1] = (short)f2bf(f0.y - 0.5f);
        v0[2] = (short)f2bf(f0.z - 0.5f); v0[3] = (short)f2bf(f0.w - 0.5f);
        v0[4] = (short)f2bf(f1.x - 0.5f); v0[5] = (short)f2bf(f1.y - 0.5f);
        v0[6] = (short)f2bf(f1.z - 0.5f); v0[7] = (short)f2bf(f1.w - 0.5f);
        v1[0] = (short)f2bf(f2.x - 0.5f); v1[1] = (short)f2bf(f2.y - 0.5f);
        v1[2] = (short)f2bf(f2.z - 0.5f); v1[3] = (short)f2bf(f2.w - 0.5f);
        v1[4] = (short)f2bf(f3.x - 0.5f); v1[5] = (short)f2bf(f3.y - 0.5f);
        v1[6] = (short)f2bf(f3.z - 0.5f); v1[7] = (short)f2bf(f3.w - 0.5f);
        *(bf16x8*)&As[arow * 32 + ahalf * 16 + 0] = v0;
        *(bf16x8*)&As[arow * 32 + ahalf * 16 + 8] = v1;
        __syncthreads();

        bf16x8 af[4], bfr[4];
#pragma unroll
        for (int i = 0; i < 4; i++)
            af[i] = *(const bf16x8*)&As[(wm + i * 16 + ln15) * 32 + quad * 8];
#pragma unroll
        for (int j = 0; j < 4; j++)
            bfr[j] = *(const bf16x8*)&Bs[(wn + j * 16 + ln15) * 32 + quad * 8];
#pragma unroll
        for (int i = 0; i < 4; i++)
#pragma unroll
            for (int j = 0; j < 4; j++)
                acc[i][j] = __builtin_amdgcn_mfma_f32_16x16x32_bf16(af[i], bfr[j], acc[i][j], 0, 0, 0);
    }

    // epilogue: +bias, tanh, bf16 store. C/D layout: col=lane&15, row=quad*4+reg
#pragma unroll
    for (int j = 0; j < 4; j++) {
        const int col = bn + wn + j * 16 + ln15;
        const float bias = b1[col];
#pragma unroll
        for (int i = 0; i < 4; i++) {
#pragma unroll
            for (int r = 0; r < 4; r++) {
                const int row = bm + wm + i * 16 + quad * 4 + r;
                hid[(size_t)row * HDIM + col] = f2bf(tanhf(acc[i][j][r] + bias));
            }
        }
    }
}

// ---------------------------------------------------------------------------
// GEMM2 (MFMA) fused with spline epilogue.
// Block: BM=64 rows x BN=272 cols (16 splines). 4 waves; wave w owns all 64
// rows x N-subtiles {w*4 .. w*4+3} (+1 extra for wave 3): 16-20 MFMA tiles.
// After K-loop: net -> LDS (bf16, stride 280) -> per-(row,spline) epilogue.
// ---------------------------------------------------------------------------
__global__ __launch_bounds__(256) void gemm2_spline_mfma(
    const unsigned short* __restrict__ hid,   // (B,H) bf16
    const unsigned short* __restrict__ W2T,   // (8704,512) bf16 k-contiguous
    const float* __restrict__ b2,
    const float* __restrict__ x,              // x_b = cols [512,1024)
    float* __restrict__ out,
    float* __restrict__ logacc)               // (B,) zeroed
{
    __shared__ short smem[64 * 280];          // 35840 B; staging & netS union
    short* As = smem;                         // 64 x 32
    short* Bs = smem + 2048;                  // 272 x 32 (ends at 10752)

    const int bm   = blockIdx.y * 64;
    const int bcol = blockIdx.x * 272;
    const int tid  = threadIdx.x;
    const int lane = tid & 63;
    const int wave = tid >> 6;
    const int ln15 = lane & 15;
    const int quad = lane >> 4;
    const int brow = lane >> 2, bsub = lane & 3;
    const int jstart = wave * 4;
    const int jcount = (wave == 3) ? 5 : 4;

    f32x4 acc[4][5];
#pragma unroll
    for (int i = 0; i < 4; i++)
#pragma unroll
        for (int j = 0; j < 5; j++) acc[i][j] = (f32x4){0.f, 0.f, 0.f, 0.f};

    for (int k0 = 0; k0 < HDIM; k0 += 32) {
        __syncthreads();
        // A: one 16-row chunk per wave (64 rows total)
        GLD16(&hid[(size_t)(bm + wave * 16 + brow) * HDIM + k0 + bsub * 8],
              &As[wave * 512]);
        // B: 17 chunks of 16 rows; wave w stages the rows of tiles it consumes
        for (int c = 0; c < jcount; ++c) {
            const int chunk = jstart + c;     // 0..16
            GLD16(&W2T[(size_t)(bcol + chunk * 16 + brow) * HDIM + k0 + bsub * 8],
                  &Bs[chunk * 512]);
        }
        __syncthreads();

        bf16x8 af[4];
#pragma unroll
        for (int i = 0; i < 4; i++)
            af[i] = *(const bf16x8*)&As[(i * 16 + ln15) * 32 + quad * 8];

#define KSTEP(JC)                                                               \
        _Pragma("unroll") for (int j = 0; j < (JC); ++j) {                      \
            bf16x8 bfr = *(const bf16x8*)&Bs[((jstart + j) * 16 + ln15) * 32 + quad * 8]; \
            _Pragma("unroll") for (int i = 0; i < 4; ++i)                       \
                acc[i][j] = __builtin_amdgcn_mfma_f32_16x16x32_bf16(af[i], bfr, acc[i][j], 0, 0, 0); \
        }
        if (wave == 3) { KSTEP(5) } else { KSTEP(4) }
#undef KSTEP
    }

    // ---- phase 1: bias + tanh -> netS (bf16, stride 280) ----
    __syncthreads();   // staging LDS reads done before overwrite
#define EPI1(JC)                                                                \
    _Pragma("unroll") for (int j = 0; j < (JC); ++j) {                          \
        const int jj = jstart + j;                                              \
        const int col_l = jj * 16 + ln15;                                       \
        const float bias = b2[bcol + col_l];                                    \
        _Pragma("unroll") for (int i = 0; i < 4; ++i)                           \
            _Pragma("unroll") for (int r = 0; r < 4; ++r) {                     \
                const int row_l = i * 16 + quad * 4 + r;                        \
                smem[row_l * 280 + col_l] = (short)f2bf(tanhf(acc[i][j][r] + bias)); \
            }                                                                   \
    }
    if (wave == 3) { EPI1(5) } else { EPI1(4) }
#undef EPI1
    __syncthreads();

    // ---- phase 2: spline math per (row, spline); 256 thr = 16 sp x 16 rows x4 ----
    const int sp = tid & 15;
    const int r0 = tid >> 4;
    const int sglob = blockIdx.x * 16 + sp;
    for (int t = 0; t < 4; ++t) {
        const int row_l = t * 16 + r0;
        const int row = bm + row_l;
        float nv[17];
#pragma unroll
        for (int c = 0; c < 17; c++)
            nv[c] = bf2f((unsigned short)smem[row_l * 280 + sp * 17 + c]);

        // softmax over nv[9..16]
        float m = nv[9];
#pragma unroll
        for (int c = 10; c < 17; c++) m = fmaxf(m, nv[c]);
        float e[8], se = 0.f;
#pragma unroll
        for (int c = 0; c < 8; c++) { e[c] = expf(nv[9 + c] - m); se += e[c]; }
        const float inv_se = 1.f / se;
        float wn[8];
#pragma unroll
        for (int c = 0; c < 8; c++) wn[c] = e[c] * inv_se;

        float eh[9];
#pragma unroll
        for (int j = 0; j < 9; j++) eh[j] = expf(nv[j]);
        float denom = 0.f;
#pragma unroll
        for (int c = 0; c < 8; c++) denom += 0.5f * wn[c] * (eh[c] + eh[c + 1]);
        const float invden = 1.f / denom;
        float hn[9];
#pragma unroll
        for (int j = 0; j < 9; j++) hn[j] = eh[j] * invden;

        const float xb = x[(size_t)row * (2 * SDIM) + SDIM + sglob];

        // knot scan (verified round 1): last c with x_knots[c] < xb
        float xk = -EPSK, pk = 0.f;
        float selw = wn[0], selh = hn[0], selh1 = hn[1], selx = xk, selp = pk;
#pragma unroll
        for (int c = 0; c < 8; c++) {
            const bool tt = (xk < xb);
            selw  = tt ? wn[c]     : selw;
            selh  = tt ? hn[c]     : selh;
            selh1 = tt ? hn[c + 1] : selh1;
            selx  = tt ? xk        : selx;
            selp  = tt ? pk        : selp;
            xk += wn[c];
            pk += 0.5f * wn[c] * (hn[c] + hn[c + 1]);
        }
        const float alpha = (xb - selx) / selw;
        const float phib = selp + alpha * selh * selw
                         + 0.5f * alpha * alpha * (selh1 - selh) * selw;
        out[(size_t)row * (2 * SDIM) + SDIM + sglob] = phib;

        float lg = logf(selh + alpha * (selh1 - selh));
        lg += __shfl_xor(lg, 1);
        lg += __shfl_xor(lg, 2);
        lg += __shfl_xor(lg, 4);
        lg += __shfl_xor(lg, 8);
        if (sp == 0) atomicAdd(&logacc[row], lg);
    }
}

// ---------------------------------------------------------------------------
// Finalize: copy x_a into out[:, :512]; tail = log_density - logacc
// ---------------------------------------------------------------------------
__global__ __launch_bounds__(256) void finalize_k(
    const float* __restrict__ x,
    const float* __restrict__ logd,
    const float* __restrict__ logacc,
    float* __restrict__ out)
{
    const int t = blockIdx.x * 256 + threadIdx.x;   // 8192*128 threads
    const int b = t >> 7;
    const int j = (t & 127) * 4;
    float4 v = *(const float4*)&x[(size_t)b * (2 * SDIM) + j];
    *(float4*)&out[(size_t)b * (2 * SDIM) + j] = v;
    if ((t & 127) == 0)
        out[(size_t)BROWS * (2 * SDIM) + b] = logd[b] - logacc[b];
}

// ---------------------------------------------------------------------------
extern "C" void kernel_launch(void* const* d_in, const int* in_sizes, int n_in,
                              void* d_out, int out_size, void* d_ws, size_t ws_size,
                              hipStream_t stream) {
    const float* x    = (const float*)d_in[0];
    const float* logd = (const float*)d_in[1];
    const float* W1   = (const float*)d_in[2];
    const float* b1   = (const float*)d_in[3];
    const float* W2   = (const float*)d_in[4];
    const float* b2   = (const float*)d_in[5];
    float* out = (float*)d_out;

    // ws layout (17.03 MiB total)
    char* ws = (char*)d_ws;
    float*          logacc = (float*)ws;                            // 32768 B
    unsigned short* W1T    = (unsigned short*)(ws + 32768);         // 512x512 bf16
    unsigned short* W2T    = (unsigned short*)(ws + 557056);        // 8704x512 bf16
    unsigned short* hid    = (unsigned short*)(ws + 9469952);       // 8192x512 bf16

    hipMemsetAsync(logacc, 0, BROWS * sizeof(float), stream);
    transpose_to_bf16<<<dim3(16, 16),  256, 0, stream>>>(W1, W1T, 512, 512);
    transpose_to_bf16<<<dim3(272, 16), 256, 0, stream>>>(W2, W2T, 512, 8704);
    gemm1_mfma<<<dim3(4, 64), 256, 0, stream>>>(x, W1T, b1, hid);
    gemm2_spline_mfma<<<dim3(32, 128), 256, 0, stream>>>(hid, W2T, b2, x, out, logacc);
    finalize_k<<<4096, 256, 0, stream>>>(x, logd, logacc, out);
}

// Round 3
// 310.216 us; speedup vs baseline: 10.8082x; 1.2160x over previous
//
#include <hip/hip_runtime.h>
#include <stdint.h>
#include <math.h>

// Problem constants
#define BROWS 8192
#define SDIM  512
#define HDIM  512
#define NCOL  8704          // S*(2K+1)
#define EPSK  1e-6f

typedef __attribute__((ext_vector_type(8))) short bf16x8;   // MFMA A/B frag (4 VGPR)
typedef __attribute__((ext_vector_type(4))) short bf16x4;
typedef __attribute__((ext_vector_type(4))) float f32x4;    // MFMA C/D frag

__device__ __forceinline__ unsigned short f2bf(float f) {   // RTNE f32->bf16
    unsigned u = __float_as_uint(f);
    u += 0x7fffu + ((u >> 16) & 1u);
    return (unsigned short)(u >> 16);
}
__device__ __forceinline__ float bf2f(unsigned short s) {
    return __uint_as_float(((unsigned)s) << 16);
}
// fast tanh: (e^{2x}-1)/(e^{2x}+1), clamp 2x to +-30 so e stays finite (no inf*0 NaN)
__device__ __forceinline__ float ftanh(float x) {
    float t = fminf(fmaxf(2.f * x, -30.f), 30.f);
    float e = __expf(t);                          // v_exp_f32 path
    return (e - 1.f) * __builtin_amdgcn_rcpf(e + 1.f);
}

// async global->LDS, 16B per lane; LDS dst must be wave-uniform (lane*16 appended by HW)
#define GLD16(g, l)                                                         \
    __builtin_amdgcn_global_load_lds(                                       \
        (const __attribute__((address_space(1))) void*)(g),                 \
        (__attribute__((address_space(3))) void*)(l), 16, 0, 0)

// ---------------------------------------------------------------------------
// Prep: out[C][R] (bf16) = transpose of in[R][C] (f32). 32x32 LDS tiles. (W1)
// ---------------------------------------------------------------------------
__global__ __launch_bounds__(256) void transpose_to_bf16(
    const float* __restrict__ in, unsigned short* __restrict__ out,
    int R, int C)
{
    __shared__ float tile[32 * 33];
    const int cb = blockIdx.x * 32;
    const int rb = blockIdx.y * 32;
    const int t  = threadIdx.x;
    const int ty = t >> 3, tx = (t & 7) * 4;
    float4 v = *(const float4*)&in[(size_t)(rb + ty) * C + cb + tx];
    tile[ty * 33 + tx + 0] = v.x;
    tile[ty * 33 + tx + 1] = v.y;
    tile[ty * 33 + tx + 2] = v.z;
    tile[ty * 33 + tx + 3] = v.w;
    __syncthreads();
    const int oy = t >> 3, ox = (t & 7) * 4;
    bf16x4 o;
    o[0] = (short)f2bf(tile[(ox + 0) * 33 + oy]);
    o[1] = (short)f2bf(tile[(ox + 1) * 33 + oy]);
    o[2] = (short)f2bf(tile[(ox + 2) * 33 + oy]);
    o[3] = (short)f2bf(tile[(ox + 3) * 33 + oy]);
    *(bf16x4*)&out[(size_t)(cb + oy) * R + rb + ox] = o;
}

// ---------------------------------------------------------------------------
// Pack W2 (512 x 8704 f32) -> W2p bf16 in the exact per-(colblk,K-step) LDS
// image: [colblk(32)][kk(16)][chunk(17)][r(16)][e(32)], element =
// W2[kk*32+e][colblk*272 + chunk*16 + r].  One block per (ct=colblk*17+chunk, kk).
// ---------------------------------------------------------------------------
__global__ __launch_bounds__(256) void pack_w2(
    const float* __restrict__ W2, unsigned short* __restrict__ W2p)
{
    __shared__ float tile[32][17];        // [e][r], pad to 17
    const int ct = blockIdx.x;            // 0..543
    const int kk = blockIdx.y;            // 0..15
    const int t  = threadIdx.x;
    const int colbase = ct * 16;          // = colblk*272 + chunk*16
    // load 32 k-rows x 16 cols (2 floats per thread, coalesced)
    {
        const int k32 = t >> 3;           // 0..31
        const int c2  = (t & 7) * 2;      // 0..14
        float2 v = *(const float2*)&W2[(size_t)(kk * 32 + k32) * NCOL + colbase + c2];
        tile[k32][c2 + 0] = v.x;
        tile[k32][c2 + 1] = v.y;
    }
    __syncthreads();
    const int colblk = ct / 17;
    const int chunk  = ct - colblk * 17;
    const size_t off = (((size_t)colblk * 16 + kk) * 17 + chunk) * 512;
    const int r  = t >> 4;                // 0..15
    const int e2 = (t & 15) * 2;          // 0..30
    ushort2 o;
    o.x = f2bf(tile[e2 + 0][r]);
    o.y = f2bf(tile[e2 + 1][r]);
    *(ushort2*)&W2p[off + (size_t)r * 32 + e2] = o;
}

// ---------------------------------------------------------------------------
// GEMM1 (MFMA): hid = bf16(tanh((x_a-0.5) @ W1 + b1))
// 128x128 tile, BK=32, 4 waves (2x2), each 64x64 = 16 MFMA tiles.
// ---------------------------------------------------------------------------
__global__ __launch_bounds__(256) void gemm1_mfma(
    const float* __restrict__ x,
    const unsigned short* __restrict__ W1T,   // (H,S) bf16 k-contiguous
    const float* __restrict__ b1,
    unsigned short* __restrict__ hid)         // (B,H) bf16
{
    __shared__ short As[128 * 32];
    __shared__ short Bs[128 * 32];
    const int bm   = blockIdx.y * 128;
    const int bn   = blockIdx.x * 128;
    const int tid  = threadIdx.x;
    const int lane = tid & 63;
    const int wave = tid >> 6;
    const int ln15 = lane & 15;
    const int quad = lane >> 4;
    const int wm   = (wave >> 1) * 64;
    const int wn   = (wave & 1) * 64;
    const int arow = tid >> 1, ahalf = tid & 1;
    const int brow = lane >> 2, bsub = lane & 3;

    f32x4 acc[4][4];
#pragma unroll
    for (int i = 0; i < 4; i++)
#pragma unroll
        for (int j = 0; j < 4; j++) acc[i][j] = (f32x4){0.f, 0.f, 0.f, 0.f};

    for (int k0 = 0; k0 < SDIM; k0 += 32) {
        const float4* xq = (const float4*)&x[(size_t)(bm + arow) * (2 * SDIM) + k0 + ahalf * 16];
        float4 f0 = xq[0], f1 = xq[1], f2 = xq[2], f3 = xq[3];
        __syncthreads();
#pragma unroll
        for (int c = 0; c < 2; c++) {
            const int chunk = wave * 2 + c;
            GLD16(&W1T[(size_t)(bn + chunk * 16 + brow) * SDIM + k0 + bsub * 8],
                  &Bs[chunk * 512]);
        }
        bf16x8 v0, v1;
        v0[0] = (short)f2bf(f0.x - 0.5f); v0[1] = (short)f2bf(f0.y - 0.5f);
        v0[2] = (short)f2bf(f0.z - 0.5f); v0[3] = (short)f2bf(f0.w - 0.5f);
        v0[4] = (short)f2bf(f1.x - 0.5f); v0[5] = (short)f2bf(f1.y - 0.5f);
        v0[6] = (short)f2bf(f1.z - 0.5f); v0[7] = (short)f2bf(f1.w - 0.5f);
        v1[0] = (short)f2bf(f2.x - 0.5f); v1[1] = (short)f2bf(f2.y - 0.5f);
        v1[2] = (short)f2bf(f2.z - 0.5f); v1[3] = (short)f2bf(f2.w - 0.5f);
        v1[4] = (short)f2bf(f3.x - 0.5f); v1[5] = (short)f2bf(f3.y - 0.5f);
        v1[6] = (short)f2bf(f3.z - 0.5f); v1[7] = (short)f2bf(f3.w - 0.5f);
        *(bf16x8*)&As[arow * 32 + ahalf * 16 + 0] = v0;
        *(bf16x8*)&As[arow * 32 + ahalf * 16 + 8] = v1;
        __syncthreads();

        bf16x8 af[4], bfr[4];
#pragma unroll
        for (int i = 0; i < 4; i++)
            af[i] = *(const bf16x8*)&As[(wm + i * 16 + ln15) * 32 + quad * 8];
#pragma unroll
        for (int j = 0; j < 4; j++)
            bfr[j] = *(const bf16x8*)&Bs[(wn + j * 16 + ln15) * 32 + quad * 8];
#pragma unroll
        for (int i = 0; i < 4; i++)
#pragma unroll
            for (int j = 0; j < 4; j++)
                acc[i][j] = __builtin_amdgcn_mfma_f32_16x16x32_bf16(af[i], bfr[j], acc[i][j], 0, 0, 0);
    }

#pragma unroll
    for (int j = 0; j < 4; j++) {
        const int col = bn + wn + j * 16 + ln15;
        const float bias = b1[col];
#pragma unroll
        for (int i = 0; i < 4; i++) {
#pragma unroll
            for (int r = 0; r < 4; r++) {
                const int row = bm + wm + i * 16 + quad * 4 + r;
                hid[(size_t)row * HDIM + col] = f2bf(ftanh(acc[i][j][r] + bias));
            }
        }
    }
}

// ---------------------------------------------------------------------------
// GEMM2 (MFMA) fused with spline epilogue. BM=64 x BN=272 (16 splines),
// 4 waves; wave w owns 64 rows x tiles {w*4..} (wave 3 gets 5). B staged from
// the packed W2p image (contiguous per K-step, trivial addressing).
// ---------------------------------------------------------------------------
__global__ __launch_bounds__(256) void gemm2_spline_mfma(
    const unsigned short* __restrict__ hid,   // (B,H) bf16
    const unsigned short* __restrict__ W2p,   // packed, see pack_w2
    const float* __restrict__ b2,
    const float* __restrict__ x,              // x_b = cols [512,1024)
    float* __restrict__ out,
    float* __restrict__ logacc)               // (B,) zeroed
{
    __shared__ short smem[64 * 280];          // 35840 B; staging & netS union
    short* As = smem;                         // 64 x 32
    short* Bs = smem + 2048;                  // 17 chunks x 512

    const int bm   = blockIdx.y * 64;
    const int tid  = threadIdx.x;
    const int lane = tid & 63;
    const int wave = tid >> 6;
    const int ln15 = lane & 15;
    const int quad = lane >> 4;
    const int brow = lane >> 2, bsub = lane & 3;
    const int jstart = wave * 4;
    const int jcount = (wave == 3) ? 5 : 4;
    const int bcol = blockIdx.x * 272;

    f32x4 acc[4][5];
#pragma unroll
    for (int i = 0; i < 4; i++)
#pragma unroll
        for (int j = 0; j < 5; j++) acc[i][j] = (f32x4){0.f, 0.f, 0.f, 0.f};

    // packed-B base for this colblock: + kk*17*512 per K-step, + lane*16 B
    const unsigned short* bbase =
        W2p + ((size_t)blockIdx.x * 16) * 17 * 512 + (size_t)lane * 8;

    for (int k0 = 0; k0 < HDIM; k0 += 32) {
        const unsigned short* bk = bbase + (size_t)(k0 >> 5) * (17 * 512);
        __syncthreads();
        GLD16(&hid[(size_t)(bm + wave * 16 + brow) * HDIM + k0 + bsub * 8],
              &As[wave * 512]);
        for (int c = 0; c < jcount; ++c) {
            const int chunk = jstart + c;
            GLD16(bk + (size_t)chunk * 512, &Bs[chunk * 512]);
        }
        __syncthreads();

        bf16x8 af[4];
#pragma unroll
        for (int i = 0; i < 4; i++)
            af[i] = *(const bf16x8*)&As[(i * 16 + ln15) * 32 + quad * 8];

#define KSTEP(JC)                                                               \
        _Pragma("unroll") for (int j = 0; j < (JC); ++j) {                      \
            bf16x8 bfr = *(const bf16x8*)&Bs[((jstart + j) * 16 + ln15) * 32 + quad * 8]; \
            _Pragma("unroll") for (int i = 0; i < 4; ++i)                       \
                acc[i][j] = __builtin_amdgcn_mfma_f32_16x16x32_bf16(af[i], bfr, acc[i][j], 0, 0, 0); \
        }
        if (wave == 3) { KSTEP(5) } else { KSTEP(4) }
#undef KSTEP
    }

    // ---- phase 1: bias + fast-tanh -> netS (bf16, stride 280) ----
    __syncthreads();
#define EPI1(JC)                                                                \
    _Pragma("unroll") for (int j = 0; j < (JC); ++j) {                          \
        const int jj = jstart + j;                                              \
        const int col_l = jj * 16 + ln15;                                       \
        const float bias = b2[bcol + col_l];                                    \
        _Pragma("unroll") for (int i = 0; i < 4; ++i)                           \
            _Pragma("unroll") for (int r = 0; r < 4; ++r) {                     \
                const int row_l = i * 16 + quad * 4 + r;                        \
                smem[row_l * 280 + col_l] = (short)f2bf(ftanh(acc[i][j][r] + bias)); \
            }                                                                   \
    }
    if (wave == 3) { EPI1(5) } else { EPI1(4) }
#undef EPI1
    __syncthreads();

    // ---- phase 2: spline math per (row, spline) ----
    const int sp = tid & 15;
    const int r0 = tid >> 4;
    const int sglob = blockIdx.x * 16 + sp;
    for (int t = 0; t < 4; ++t) {
        const int row_l = t * 16 + r0;
        const int row = bm + row_l;
        float nv[17];
#pragma unroll
        for (int c = 0; c < 17; c++)
            nv[c] = bf2f((unsigned short)smem[row_l * 280 + sp * 17 + c]);

        // softmax over nv[9..16]
        float m = nv[9];
#pragma unroll
        for (int c = 10; c < 17; c++) m = fmaxf(m, nv[c]);
        float e[8], se = 0.f;
#pragma unroll
        for (int c = 0; c < 8; c++) { e[c] = __expf(nv[9 + c] - m); se += e[c]; }
        const float inv_se = __builtin_amdgcn_rcpf(se);
        float wn[8];
#pragma unroll
        for (int c = 0; c < 8; c++) wn[c] = e[c] * inv_se;

        float eh[9];
#pragma unroll
        for (int j = 0; j < 9; j++) eh[j] = __expf(nv[j]);
        float denom = 0.f;
#pragma unroll
        for (int c = 0; c < 8; c++) denom += 0.5f * wn[c] * (eh[c] + eh[c + 1]);
        const float invden = __builtin_amdgcn_rcpf(denom);
        float hn[9];
#pragma unroll
        for (int j = 0; j < 9; j++) hn[j] = eh[j] * invden;

        const float xb = x[(size_t)row * (2 * SDIM) + SDIM + sglob];

        // knot scan: last c with x_knots[c] < xb
        float xk = -EPSK, pk = 0.f;
        float selw = wn[0], selh = hn[0], selh1 = hn[1], selx = xk, selp = pk;
#pragma unroll
        for (int c = 0; c < 8; c++) {
            const bool tt = (xk < xb);
            selw  = tt ? wn[c]     : selw;
            selh  = tt ? hn[c]     : selh;
            selh1 = tt ? hn[c + 1] : selh1;
            selx  = tt ? xk        : selx;
            selp  = tt ? pk        : selp;
            xk += wn[c];
            pk += 0.5f * wn[c] * (hn[c] + hn[c + 1]);
        }
        const float alpha = (xb - selx) * __builtin_amdgcn_rcpf(selw);
        const float phib = selp + alpha * selh * selw
                         + 0.5f * alpha * alpha * (selh1 - selh) * selw;
        out[(size_t)row * (2 * SDIM) + SDIM + sglob] = phib;

        float lg = __logf(selh + alpha * (selh1 - selh));
        lg += __shfl_xor(lg, 1);
        lg += __shfl_xor(lg, 2);
        lg += __shfl_xor(lg, 4);
        lg += __shfl_xor(lg, 8);
        if (sp == 0) atomicAdd(&logacc[row], lg);
    }
}

// ---------------------------------------------------------------------------
// Finalize: copy x_a into out[:, :512]; tail = log_density - logacc
// ---------------------------------------------------------------------------
__global__ __launch_bounds__(256) void finalize_k(
    const float* __restrict__ x,
    const float* __restrict__ logd,
    const float* __restrict__ logacc,
    float* __restrict__ out)
{
    const int t = blockIdx.x * 256 + threadIdx.x;
    const int b = t >> 7;
    const int j = (t & 127) * 4;
    float4 v = *(const float4*)&x[(size_t)b * (2 * SDIM) + j];
    *(float4*)&out[(size_t)b * (2 * SDIM) + j] = v;
    if ((t & 127) == 0)
        out[(size_t)BROWS * (2 * SDIM) + b] = logd[b] - logacc[b];
}

// ---------------------------------------------------------------------------
extern "C" void kernel_launch(void* const* d_in, const int* in_sizes, int n_in,
                              void* d_out, int out_size, void* d_ws, size_t ws_size,
                              hipStream_t stream) {
    const float* x    = (const float*)d_in[0];
    const float* logd = (const float*)d_in[1];
    const float* W1   = (const float*)d_in[2];
    const float* b1   = (const float*)d_in[3];
    const float* W2   = (const float*)d_in[4];
    const float* b2   = (const float*)d_in[5];
    float* out = (float*)d_out;

    // ws layout (17.03 MiB total)
    char* ws = (char*)d_ws;
    float*          logacc = (float*)ws;                            // 32768 B
    unsigned short* W1T    = (unsigned short*)(ws + 32768);         // 512x512 bf16
    unsigned short* W2p    = (unsigned short*)(ws + 557056);        // 8704x512 bf16 packed
    unsigned short* hid    = (unsigned short*)(ws + 9469952);       // 8192x512 bf16

    hipMemsetAsync(logacc, 0, BROWS * sizeof(float), stream);
    transpose_to_bf16<<<dim3(16, 16), 256, 0, stream>>>(W1, W1T, 512, 512);
    pack_w2<<<dim3(544, 16), 256, 0, stream>>>(W2, W2p);
    gemm1_mfma<<<dim3(4, 64), 256, 0, stream>>>(x, W1T, b1, hid);
    gemm2_spline_mfma<<<dim3(32, 128), 256, 0, stream>>>(hid, W2p, b2, x, out, logacc);
    finalize_k<<<4096, 256, 0, stream>>>(x, logd, logacc, out);
}

// Round 4
// 291.485 us; speedup vs baseline: 11.5028x; 1.0643x over previous
//
#include <hip/hip_runtime.h>
#include <stdint.h>
#include <math.h>

// Problem constants
#define BROWS 8192
#define SDIM  512
#define HDIM  512
#define NCOL  8704          // S*(2K+1)
#define EPSK  1e-6f
#define LOG2E  1.442695041f
#define TWOL2E 2.885390082f
#define LN2    0.6931471806f

typedef __attribute__((ext_vector_type(8))) short bf16x8;   // MFMA A/B frag (4 VGPR)
typedef __attribute__((ext_vector_type(4))) short bf16x4;
typedef __attribute__((ext_vector_type(4))) float f32x4;    // MFMA C/D frag

__device__ __forceinline__ unsigned short f2bf(float f) {   // RTNE f32->bf16
    unsigned u = __float_as_uint(f);
    u += 0x7fffu + ((u >> 16) & 1u);
    return (unsigned short)(u >> 16);
}
__device__ __forceinline__ unsigned short f2bf_fast(float f) { // round-half-up (2 inst)
    return (unsigned short)((__float_as_uint(f) + 0x8000u) >> 16);
}
__device__ __forceinline__ float bf2f(unsigned short s) {
    return __uint_as_float(((unsigned)s) << 16);
}
#define EXP2F(x) __builtin_amdgcn_exp2f(x)   // v_exp_f32 (base 2)
#define LOG2F(x) __builtin_amdgcn_logf(x)    // v_log_f32 (base 2)
#define RCPF(x)  __builtin_amdgcn_rcpf(x)

// fast tanh: (e-1)/(e+1), e = 2^(2*log2e*x); clamp keeps e finite
__device__ __forceinline__ float ftanh(float x) {
    float t = fminf(fmaxf(TWOL2E * x, -43.f), 43.f);
    float e = EXP2F(t);
    return (e - 1.f) * RCPF(e + 1.f);
}
// log2e * tanh(acc + bias), bias pre-scaled by 2*log2e; num = e*L - L fused
__device__ __forceinline__ float ftanh_l2e(float acc, float bias2L) {
    float t = fminf(fmaxf(fmaf(acc, TWOL2E, bias2L), -43.f), 43.f);
    float e = EXP2F(t);
    return fmaf(e, LOG2E, -LOG2E) * RCPF(e + 1.f);
}

// async global->LDS, 16B per lane; LDS dst must be wave-uniform (lane*16 appended by HW)
#define GLD16(g, l)                                                         \
    __builtin_amdgcn_global_load_lds(                                       \
        (const __attribute__((address_space(1))) void*)(g),                 \
        (__attribute__((address_space(3))) void*)(l), 16, 0, 0)

// ---------------------------------------------------------------------------
// Prep: out[C][R] (bf16) = transpose of in[R][C] (f32). 32x32 LDS tiles. (W1)
// ---------------------------------------------------------------------------
__global__ __launch_bounds__(256) void transpose_to_bf16(
    const float* __restrict__ in, unsigned short* __restrict__ out,
    int R, int C)
{
    __shared__ float tile[32 * 33];
    const int cb = blockIdx.x * 32;
    const int rb = blockIdx.y * 32;
    const int t  = threadIdx.x;
    const int ty = t >> 3, tx = (t & 7) * 4;
    float4 v = *(const float4*)&in[(size_t)(rb + ty) * C + cb + tx];
    tile[ty * 33 + tx + 0] = v.x;
    tile[ty * 33 + tx + 1] = v.y;
    tile[ty * 33 + tx + 2] = v.z;
    tile[ty * 33 + tx + 3] = v.w;
    __syncthreads();
    const int oy = t >> 3, ox = (t & 7) * 4;
    bf16x4 o;
    o[0] = (short)f2bf(tile[(ox + 0) * 33 + oy]);
    o[1] = (short)f2bf(tile[(ox + 1) * 33 + oy]);
    o[2] = (short)f2bf(tile[(ox + 2) * 33 + oy]);
    o[3] = (short)f2bf(tile[(ox + 3) * 33 + oy]);
    *(bf16x4*)&out[(size_t)(cb + oy) * R + rb + ox] = o;
}

// ---------------------------------------------------------------------------
// Pack W2 (512 x 8704 f32) -> W2p bf16 per-(colblk,K-step) LDS image:
// [colblk(32)][kk(16)][chunk(17)][r(16)][e(32)]. One block per ct, kk looped.
// ---------------------------------------------------------------------------
__global__ __launch_bounds__(256) void pack_w2(
    const float* __restrict__ W2, unsigned short* __restrict__ W2p)
{
    __shared__ float tile[32][17];
    const int ct = blockIdx.x;            // 0..543
    const int t  = threadIdx.x;
    const int colbase = ct * 16;
    const int colblk = ct / 17;
    const int chunk  = ct - colblk * 17;
    const int k32 = t >> 3;               // 0..31
    const int c2  = (t & 7) * 2;          // 0..14
    const int r   = t >> 4;               // 0..15
    const int e2  = (t & 15) * 2;         // 0..30
    for (int kk = 0; kk < 16; ++kk) {
        float2 v = *(const float2*)&W2[(size_t)(kk * 32 + k32) * NCOL + colbase + c2];
        __syncthreads();
        tile[k32][c2 + 0] = v.x;
        tile[k32][c2 + 1] = v.y;
        __syncthreads();
        const size_t off = (((size_t)colblk * 16 + kk) * 17 + chunk) * 512;
        ushort2 o;
        o.x = f2bf(tile[e2 + 0][r]);
        o.y = f2bf(tile[e2 + 1][r]);
        *(ushort2*)&W2p[off + (size_t)r * 32 + e2] = o;
    }
}

// ---------------------------------------------------------------------------
// GEMM1 (MFMA): hid = bf16(tanh((x_a-0.5) @ W1 + b1))
// 64x128 tile, BK=32, grid 512 (2 blocks/CU). 4 waves 2x2, wave = 32x64.
// ---------------------------------------------------------------------------
__global__ __launch_bounds__(256) void gemm1_mfma(
    const float* __restrict__ x,
    const unsigned short* __restrict__ W1T,   // (H,S) bf16 k-contiguous
    const float* __restrict__ b1,
    unsigned short* __restrict__ hid)         // (B,H) bf16
{
    __shared__ short As[64 * 32];
    __shared__ short Bs[128 * 32];
    const int bm   = blockIdx.y * 64;
    const int bn   = blockIdx.x * 128;
    const int tid  = threadIdx.x;
    const int lane = tid & 63;
    const int wave = tid >> 6;
    const int ln15 = lane & 15;
    const int quad = lane >> 4;
    const int wm   = (wave >> 1) * 32;
    const int wn   = (wave & 1) * 64;
    const int arow = tid >> 2, aseg = tid & 3;      // A: 64 rows x 4 segs of 8
    const int brow = lane >> 2, bsub = lane & 3;

    f32x4 acc[2][4];
#pragma unroll
    for (int i = 0; i < 2; i++)
#pragma unroll
        for (int j = 0; j < 4; j++) acc[i][j] = (f32x4){0.f, 0.f, 0.f, 0.f};

    for (int k0 = 0; k0 < SDIM; k0 += 32) {
        const float4* xq = (const float4*)&x[(size_t)(bm + arow) * (2 * SDIM) + k0 + aseg * 8];
        float4 f0 = xq[0], f1 = xq[1];
        __syncthreads();
#pragma unroll
        for (int c = 0; c < 2; c++) {
            const int chunk = wave * 2 + c;         // 0..7
            GLD16(&W1T[(size_t)(bn + chunk * 16 + brow) * SDIM + k0 + bsub * 8],
                  &Bs[chunk * 512]);
        }
        bf16x8 v0;
        v0[0] = (short)f2bf_fast(f0.x - 0.5f); v0[1] = (short)f2bf_fast(f0.y - 0.5f);
        v0[2] = (short)f2bf_fast(f0.z - 0.5f); v0[3] = (short)f2bf_fast(f0.w - 0.5f);
        v0[4] = (short)f2bf_fast(f1.x - 0.5f); v0[5] = (short)f2bf_fast(f1.y - 0.5f);
        v0[6] = (short)f2bf_fast(f1.z - 0.5f); v0[7] = (short)f2bf_fast(f1.w - 0.5f);
        *(bf16x8*)&As[arow * 32 + aseg * 8] = v0;
        __syncthreads();

        bf16x8 af[2], bfr[4];
#pragma unroll
        for (int i = 0; i < 2; i++)
            af[i] = *(const bf16x8*)&As[(wm + i * 16 + ln15) * 32 + quad * 8];
#pragma unroll
        for (int j = 0; j < 4; j++)
            bfr[j] = *(const bf16x8*)&Bs[(wn + j * 16 + ln15) * 32 + quad * 8];
#pragma unroll
        for (int i = 0; i < 2; i++)
#pragma unroll
            for (int j = 0; j < 4; j++)
                acc[i][j] = __builtin_amdgcn_mfma_f32_16x16x32_bf16(af[i], bfr[j], acc[i][j], 0, 0, 0);
    }

#pragma unroll
    for (int j = 0; j < 4; j++) {
        const int col = bn + wn + j * 16 + ln15;
        const float bias = b1[col];
#pragma unroll
        for (int i = 0; i < 2; i++) {
#pragma unroll
            for (int r = 0; r < 4; r++) {
                const int row = bm + wm + i * 16 + quad * 4 + r;
                hid[(size_t)row * HDIM + col] = f2bf(ftanh(acc[i][j][r] + bias));
            }
        }
    }
}

// ---------------------------------------------------------------------------
// GEMM2 (MFMA) fused with spline epilogue. BM=64 x BN=272 (16 splines).
// netS layout: s = log2e*tanh(net), bf16, [row(64)][sp(16)][24], row stride 392.
// Epilogue works on unnormalized cumsums (see round-4 derivation).
// ---------------------------------------------------------------------------
__global__ __launch_bounds__(256) void gemm2_spline_mfma(
    const unsigned short* __restrict__ hid,   // (B,H) bf16
    const unsigned short* __restrict__ W2p,   // packed, see pack_w2
    const float* __restrict__ b2,
    const float* __restrict__ x,              // x_b = cols [512,1024)
    float* __restrict__ out,
    float* __restrict__ logacc)               // (B,) zeroed
{
    __shared__ short smem[64 * 392];          // 50176 B; staging & netS union
    short* As = smem;                         // 64 x 32
    short* Bs = smem + 2048;                  // 17 chunks x 512

    const int bm   = blockIdx.y * 64;
    const int tid  = threadIdx.x;
    const int lane = tid & 63;
    const int wave = tid >> 6;
    const int ln15 = lane & 15;
    const int quad = lane >> 4;
    const int brow = lane >> 2, bsub = lane & 3;
    const int jstart = wave * 4;
    const int jcount = (wave == 3) ? 5 : 4;
    const int bcol = blockIdx.x * 272;

    f32x4 acc[4][5];
#pragma unroll
    for (int i = 0; i < 4; i++)
#pragma unroll
        for (int j = 0; j < 5; j++) acc[i][j] = (f32x4){0.f, 0.f, 0.f, 0.f};

    const unsigned short* bbase =
        W2p + ((size_t)blockIdx.x * 16) * 17 * 512 + (size_t)lane * 8;

    for (int k0 = 0; k0 < HDIM; k0 += 32) {
        const unsigned short* bk = bbase + (size_t)(k0 >> 5) * (17 * 512);
        __syncthreads();
        GLD16(&hid[(size_t)(bm + wave * 16 + brow) * HDIM + k0 + bsub * 8],
              &As[wave * 512]);
        for (int c = 0; c < jcount; ++c) {
            const int chunk = jstart + c;
            GLD16(bk + (size_t)chunk * 512, &Bs[chunk * 512]);
        }
        __syncthreads();

        bf16x8 af[4];
#pragma unroll
        for (int i = 0; i < 4; i++)
            af[i] = *(const bf16x8*)&As[(i * 16 + ln15) * 32 + quad * 8];

#define KSTEP(JC)                                                               \
        _Pragma("unroll") for (int j = 0; j < (JC); ++j) {                      \
            bf16x8 bfr = *(const bf16x8*)&Bs[((jstart + j) * 16 + ln15) * 32 + quad * 8]; \
            _Pragma("unroll") for (int i = 0; i < 4; ++i)                       \
                acc[i][j] = __builtin_amdgcn_mfma_f32_16x16x32_bf16(af[i], bfr, acc[i][j], 0, 0, 0); \
        }
        if (wave == 3) { KSTEP(5) } else { KSTEP(4) }
#undef KSTEP
    }

    // ---- phase 1: s = log2e*tanh(acc+bias) -> netS [row][sp][24] bf16 ----
    __syncthreads();
#define EPI1(JC)                                                                \
    _Pragma("unroll") for (int j = 0; j < (JC); ++j) {                          \
        const int col_l = (jstart + j) * 16 + ln15;                             \
        const int spc   = (col_l * 241) >> 12;   /* col_l/17, col_l<272 */      \
        const int cc    = col_l - spc * 17;                                     \
        const int basej = spc * 24 + cc;                                        \
        const float bias2L = b2[bcol + col_l] * TWOL2E;                         \
        _Pragma("unroll") for (int i = 0; i < 4; ++i)                           \
            _Pragma("unroll") for (int r = 0; r < 4; ++r) {                     \
                const int row_l = i * 16 + quad * 4 + r;                        \
                smem[row_l * 392 + basej] =                                     \
                    (short)f2bf_fast(ftanh_l2e(acc[i][j][r], bias2L));          \
            }                                                                   \
    }
    if (wave == 3) { EPI1(5) } else { EPI1(4) }
#undef EPI1
    __syncthreads();

    // ---- phase 2: spline math per (row, spline), unnormalized formulation ----
    const int sp = tid & 15;
    const int r0 = tid >> 4;
    const int sglob = blockIdx.x * 16 + sp;
    for (int t = 0; t < 4; ++t) {
        const int row_l = t * 16 + r0;
        const int row = bm + row_l;
        const int base2 = row_l * 392 + sp * 24;
        bf16x8 p0 = *(const bf16x8*)&smem[base2];
        bf16x8 p1 = *(const bf16x8*)&smem[base2 + 8];
        const short p2 = smem[base2 + 16];

        float s[17];
#pragma unroll
        for (int c = 0; c < 8; c++) s[c] = bf2f((unsigned short)p0[c]);
#pragma unroll
        for (int c = 0; c < 8; c++) s[8 + c] = bf2f((unsigned short)p1[c]);
        s[16] = bf2f((unsigned short)p2);

        // eh[j] = exp(h_raw[j]) (unnormalized), e[c] = exp(w_raw[c]) (no max
        // subtraction needed: |s| < 1.45 since tanh-bounded)
        float eh[9], e[8];
#pragma unroll
        for (int j = 0; j < 9; j++) eh[j] = EXP2F(s[j]);
#pragma unroll
        for (int c = 0; c < 8; c++) e[c]  = EXP2F(s[9 + c]);

        // inclusive cumsums of e and u = e*(eh+eh1)
        float cum_e[8], cum_u[8];
        cum_e[0] = e[0];
        cum_u[0] = e[0] * (eh[0] + eh[1]);
#pragma unroll
        for (int c = 1; c < 8; c++) {
            cum_e[c] = cum_e[c - 1] + e[c];
            cum_u[c] = fmaf(e[c], eh[c] + eh[c + 1], cum_u[c - 1]);
        }
        const float se = cum_e[7];
        const float su = cum_u[7];

        const float xb  = x[(size_t)row * (2 * SDIM) + SDIM + sglob];
        const float thr = xb * se;          // compare vs unnormalized knots

        // scan: k = last c with knot_c < xb, knot_c = cum_e[c-1]/se
        float selE = e[0], selEH = eh[0], selEH1 = eh[1];
        float selCE = -EPSK * se, selCU = 0.f;
#pragma unroll
        for (int c = 1; c < 8; c++) {
            const bool tt = (cum_e[c - 1] < thr);
            selE   = tt ? e[c]         : selE;
            selEH  = tt ? eh[c]        : selEH;
            selEH1 = tt ? eh[c + 1]    : selEH1;
            selCE  = tt ? cum_e[c - 1] : selCE;
            selCU  = tt ? cum_u[c - 1] : selCU;
        }

        const float alpha = (thr - selCE) * RCPF(selE);
        const float dlt   = selEH1 - selEH;
        const float su_inv = RCPF(su);
        // phi = (cum_u[k-1] + 2a*e*eh + a^2*e*dlt)/su
        float p = fmaf(2.f * alpha, selE * selEH, selCU);
        p = fmaf(alpha * alpha, selE * dlt, p);
        out[(size_t)row * (2 * SDIM) + SDIM + sglob] = p * su_inv;

        // log(h_k + a*(h_{k+1}-h_k)) with h = eh * 2*se/su
        const float g = fmaf(alpha, dlt, selEH) * (2.f * se * su_inv);
        float lg = LOG2F(g);
        lg += __shfl_xor(lg, 1);
        lg += __shfl_xor(lg, 2);
        lg += __shfl_xor(lg, 4);
        lg += __shfl_xor(lg, 8);
        if (sp == 0) atomicAdd(&logacc[row], lg * LN2);
    }
}

// ---------------------------------------------------------------------------
// Finalize: copy x_a into out[:, :512]; tail = log_density - logacc
// ---------------------------------------------------------------------------
__global__ __launch_bounds__(256) void finalize_k(
    const float* __restrict__ x,
    const float* __restrict__ logd,
    const float* __restrict__ logacc,
    float* __restrict__ out)
{
    const int t = blockIdx.x * 256 + threadIdx.x;
    const int b = t >> 7;
    const int j = (t & 127) * 4;
    float4 v = *(const float4*)&x[(size_t)b * (2 * SDIM) + j];
    *(float4*)&out[(size_t)b * (2 * SDIM) + j] = v;
    if ((t & 127) == 0)
        out[(size_t)BROWS * (2 * SDIM) + b] = logd[b] - logacc[b];
}

// ---------------------------------------------------------------------------
extern "C" void kernel_launch(void* const* d_in, const int* in_sizes, int n_in,
                              void* d_out, int out_size, void* d_ws, size_t ws_size,
                              hipStream_t stream) {
    const float* x    = (const float*)d_in[0];
    const float* logd = (const float*)d_in[1];
    const float* W1   = (const float*)d_in[2];
    const float* b1   = (const float*)d_in[3];
    const float* W2   = (const float*)d_in[4];
    const float* b2   = (const float*)d_in[5];
    float* out = (float*)d_out;

    // ws layout (17.03 MiB total)
    char* ws = (char*)d_ws;
    float*          logacc = (float*)ws;                            // 32768 B
    unsigned short* W1T    = (unsigned short*)(ws + 32768);         // 512x512 bf16
    unsigned short* W2p    = (unsigned short*)(ws + 557056);        // 8704x512 bf16 packed
    unsigned short* hid    = (unsigned short*)(ws + 9469952);       // 8192x512 bf16

    hipMemsetAsync(logacc, 0, BROWS * sizeof(float), stream);
    transpose_to_bf16<<<dim3(16, 16), 256, 0, stream>>>(W1, W1T, 512, 512);
    pack_w2<<<544, 256, 0, stream>>>(W2, W2p);
    gemm1_mfma<<<dim3(4, 128), 256, 0, stream>>>(x, W1T, b1, hid);
    gemm2_spline_mfma<<<dim3(32, 128), 256, 0, stream>>>(hid, W2p, b2, x, out, logacc);
    finalize_k<<<4096, 256, 0, stream>>>(x, logd, logacc, out);
}

// Round 5
// 260.411 us; speedup vs baseline: 12.8754x; 1.1193x over previous
//
#include <hip/hip_runtime.h>
#include <stdint.h>
#include <math.h>

// Problem constants
#define BROWS 8192
#define SDIM  512
#define HDIM  512
#define NCOL  8704          // S*(2K+1)
#define EPSK  1e-6f
#define LOG2E  1.442695041f
#define TWOL2E 2.885390082f
#define LN2    0.6931471806f

typedef __attribute__((ext_vector_type(8))) short bf16x8;   // MFMA A/B frag (4 VGPR)
typedef __attribute__((ext_vector_type(4))) short bf16x4;
typedef __attribute__((ext_vector_type(4))) float f32x4;    // MFMA C/D frag

__device__ __forceinline__ unsigned short f2bf(float f) {   // RTNE f32->bf16
    unsigned u = __float_as_uint(f);
    u += 0x7fffu + ((u >> 16) & 1u);
    return (unsigned short)(u >> 16);
}
__device__ __forceinline__ unsigned short f2bf_fast(float f) { // round-half-up (2 inst)
    return (unsigned short)((__float_as_uint(f) + 0x8000u) >> 16);
}
__device__ __forceinline__ float bf2f(unsigned short s) {
    return __uint_as_float(((unsigned)s) << 16);
}
#define EXP2F(x) __builtin_amdgcn_exp2f(x)   // v_exp_f32 (base 2)
#define LOG2F(x) __builtin_amdgcn_logf(x)    // v_log_f32 (base 2)
#define RCPF(x)  __builtin_amdgcn_rcpf(x)

// fast tanh: (e-1)/(e+1), e = 2^(2*log2e*x); clamp keeps e finite
__device__ __forceinline__ float ftanh(float x) {
    float t = fminf(fmaxf(TWOL2E * x, -43.f), 43.f);
    float e = EXP2F(t);
    return (e - 1.f) * RCPF(e + 1.f);
}
// log2e * tanh(acc + bias), bias pre-scaled by 2*log2e
__device__ __forceinline__ float ftanh_l2e(float acc, float bias2L) {
    float t = fminf(fmaxf(fmaf(acc, TWOL2E, bias2L), -43.f), 43.f);
    float e = EXP2F(t);
    return fmaf(e, LOG2E, -LOG2E) * RCPF(e + 1.f);
}

// async global->LDS, 16B per lane; LDS dst is wave-uniform base + lane*16
#define GLD16(g, l)                                                         \
    __builtin_amdgcn_global_load_lds(                                       \
        (const __attribute__((address_space(1))) void*)(g),                 \
        (__attribute__((address_space(3))) void*)(l), 16, 0, 0)

// ---------------------------------------------------------------------------
// PREP (one kernel, 832 blocks):
//  blocks [0,544)    : pack W2 -> W2p image [colblk(32)][kk(16)][chunk(17)][r16][e32]
//  blocks [544,800)  : transpose W1 (512x512) -> W1T bf16 (col-major/k-contig)
//  blocks [800,832)  : out tail init: out[B*1024 + b] = logd[b]
// ---------------------------------------------------------------------------
__global__ __launch_bounds__(256) void prep_k(
    const float* __restrict__ W2, unsigned short* __restrict__ W2p,
    const float* __restrict__ W1, unsigned short* __restrict__ W1T,
    const float* __restrict__ logd, float* __restrict__ out)
{
    __shared__ float tile[32 * 33];
    const int t = threadIdx.x;
    if (blockIdx.x < 544) {
        // ---- pack W2 ----
        const int ct = blockIdx.x;            // 0..543
        const int colbase = ct * 16;
        const int colblk = ct / 17;
        const int chunk  = ct - colblk * 17;
        const int k32 = t >> 3;               // 0..31
        const int c2  = (t & 7) * 2;          // 0..14
        const int r   = t >> 4;               // 0..15
        const int e2  = (t & 15) * 2;         // 0..30
        for (int kk = 0; kk < 16; ++kk) {
            float2 v = *(const float2*)&W2[(size_t)(kk * 32 + k32) * NCOL + colbase + c2];
            __syncthreads();
            tile[k32 * 17 + c2 + 0] = v.x;
            tile[k32 * 17 + c2 + 1] = v.y;
            __syncthreads();
            const size_t off = (((size_t)colblk * 16 + kk) * 17 + chunk) * 512;
            ushort2 o;
            o.x = f2bf(tile[(e2 + 0) * 17 + r]);
            o.y = f2bf(tile[(e2 + 1) * 17 + r]);
            *(ushort2*)&W2p[off + (size_t)r * 32 + e2] = o;
        }
    } else if (blockIdx.x < 800) {
        // ---- transpose W1 to bf16 ----
        const int bt = blockIdx.x - 544;      // 0..255
        const int cb = (bt & 15) * 32;
        const int rb = (bt >> 4) * 32;
        const int ty = t >> 3, tx = (t & 7) * 4;
        float4 v = *(const float4*)&W1[(size_t)(rb + ty) * HDIM + cb + tx];
        tile[ty * 33 + tx + 0] = v.x;
        tile[ty * 33 + tx + 1] = v.y;
        tile[ty * 33 + tx + 2] = v.z;
        tile[ty * 33 + tx + 3] = v.w;
        __syncthreads();
        const int oy = t >> 3, ox = (t & 7) * 4;
        bf16x4 o;
        o[0] = (short)f2bf(tile[(ox + 0) * 33 + oy]);
        o[1] = (short)f2bf(tile[(ox + 1) * 33 + oy]);
        o[2] = (short)f2bf(tile[(ox + 2) * 33 + oy]);
        o[3] = (short)f2bf(tile[(ox + 3) * 33 + oy]);
        *(bf16x4*)&W1T[(size_t)(cb + oy) * SDIM + rb + ox] = o;
    } else {
        // ---- out tail init ----
        const int b = (blockIdx.x - 800) * 256 + t;   // 0..8191
        out[(size_t)BROWS * (2 * SDIM) + b] = logd[b];
    }
}

// ---------------------------------------------------------------------------
// GEMM1 (MFMA): hid = bf16(tanh((x_a-0.5) @ W1 + b1)); blocks with bn==0 also
// copy the staged x_a floats into out[:, :512] (fuses old finalize_k copy).
// 64x128 tile, BK=32, grid (4,128). 4 waves 2x2, wave = 32x64.
// ---------------------------------------------------------------------------
__global__ __launch_bounds__(256) void gemm1_mfma(
    const float* __restrict__ x,
    const unsigned short* __restrict__ W1T,   // (H,S) bf16 k-contiguous
    const float* __restrict__ b1,
    unsigned short* __restrict__ hid,         // (B,H) bf16
    float* __restrict__ out)
{
    __shared__ short As[64 * 32];
    __shared__ short Bs[128 * 32];
    const int bm   = blockIdx.y * 64;
    const int bn   = blockIdx.x * 128;
    const int tid  = threadIdx.x;
    const int lane = tid & 63;
    const int wave = tid >> 6;
    const int ln15 = lane & 15;
    const int quad = lane >> 4;
    const int wm   = (wave >> 1) * 32;
    const int wn   = (wave & 1) * 64;
    const int arow = tid >> 2, aseg = tid & 3;      // A: 64 rows x 4 segs of 8
    const int brow = lane >> 2, bsub = lane & 3;

    f32x4 acc[2][4];
#pragma unroll
    for (int i = 0; i < 2; i++)
#pragma unroll
        for (int j = 0; j < 4; j++) acc[i][j] = (f32x4){0.f, 0.f, 0.f, 0.f};

    for (int k0 = 0; k0 < SDIM; k0 += 32) {
        const float4* xq = (const float4*)&x[(size_t)(bm + arow) * (2 * SDIM) + k0 + aseg * 8];
        float4 f0 = xq[0], f1 = xq[1];
        if (blockIdx.x == 0) {                      // fused x_a -> out copy
            float* op = &out[(size_t)(bm + arow) * (2 * SDIM) + k0 + aseg * 8];
            *(float4*)op = f0;
            *(float4*)(op + 4) = f1;
        }
        __syncthreads();
#pragma unroll
        for (int c = 0; c < 2; c++) {
            const int chunk = wave * 2 + c;         // 0..7
            GLD16(&W1T[(size_t)(bn + chunk * 16 + brow) * SDIM + k0 + bsub * 8],
                  &Bs[chunk * 512]);
        }
        bf16x8 v0;
        v0[0] = (short)f2bf_fast(f0.x - 0.5f); v0[1] = (short)f2bf_fast(f0.y - 0.5f);
        v0[2] = (short)f2bf_fast(f0.z - 0.5f); v0[3] = (short)f2bf_fast(f0.w - 0.5f);
        v0[4] = (short)f2bf_fast(f1.x - 0.5f); v0[5] = (short)f2bf_fast(f1.y - 0.5f);
        v0[6] = (short)f2bf_fast(f1.z - 0.5f); v0[7] = (short)f2bf_fast(f1.w - 0.5f);
        *(bf16x8*)&As[arow * 32 + aseg * 8] = v0;
        __syncthreads();

        bf16x8 af[2], bfr[4];
#pragma unroll
        for (int i = 0; i < 2; i++)
            af[i] = *(const bf16x8*)&As[(wm + i * 16 + ln15) * 32 + quad * 8];
#pragma unroll
        for (int j = 0; j < 4; j++)
            bfr[j] = *(const bf16x8*)&Bs[(wn + j * 16 + ln15) * 32 + quad * 8];
#pragma unroll
        for (int i = 0; i < 2; i++)
#pragma unroll
            for (int j = 0; j < 4; j++)
                acc[i][j] = __builtin_amdgcn_mfma_f32_16x16x32_bf16(af[i], bfr[j], acc[i][j], 0, 0, 0);
    }

#pragma unroll
    for (int j = 0; j < 4; j++) {
        const int col = bn + wn + j * 16 + ln15;
        const float bias = b1[col];
#pragma unroll
        for (int i = 0; i < 2; i++) {
#pragma unroll
            for (int r = 0; r < 4; r++) {
                const int row = bm + wm + i * 16 + quad * 4 + r;
                hid[(size_t)row * HDIM + col] = f2bf(ftanh(acc[i][j][r] + bias));
            }
        }
    }
}

// ---------------------------------------------------------------------------
// GEMM2 (MFMA) fused with spline epilogue. BM=64 x BN=272 (16 splines).
// netS: s = log2e*tanh(net), bf16, [row(64)][sp(16)][24], row stride 392.
// Log-sum accumulated straight into the out tail (init'd by prep_k).
// __launch_bounds__(256,3): cap regs for 3 blocks/CU (was 172 regs = 2/CU).
// ---------------------------------------------------------------------------
__global__ __launch_bounds__(256, 3) void gemm2_spline_mfma(
    const unsigned short* __restrict__ hid,   // (B,H) bf16
    const unsigned short* __restrict__ W2p,   // packed, see prep_k
    const float* __restrict__ b2,
    const float* __restrict__ x,              // x_b = cols [512,1024)
    float* __restrict__ out)                  // [B*1024 phi | B tail]
{
    __shared__ short smem[64 * 392];          // 50176 B; staging & netS union
    short* As = smem;                         // 64 x 32
    short* Bs = smem + 2048;                  // 17 chunks x 512

    const int bm   = blockIdx.y * 64;
    const int tid  = threadIdx.x;
    const int lane = tid & 63;
    const int wave = tid >> 6;
    const int ln15 = lane & 15;
    const int quad = lane >> 4;
    const int brow = lane >> 2, bsub = lane & 3;
    const int jstart = wave * 4;
    const int jcount = (wave == 3) ? 5 : 4;
    const int bcol = blockIdx.x * 272;

    f32x4 acc[4][5];
#pragma unroll
    for (int i = 0; i < 4; i++)
#pragma unroll
        for (int j = 0; j < 5; j++) acc[i][j] = (f32x4){0.f, 0.f, 0.f, 0.f};

    const unsigned short* bbase =
        W2p + ((size_t)blockIdx.x * 16) * 17 * 512 + (size_t)lane * 8;

    for (int k0 = 0; k0 < HDIM; k0 += 32) {
        const unsigned short* bk = bbase + (size_t)(k0 >> 5) * (17 * 512);
        __syncthreads();
        GLD16(&hid[(size_t)(bm + wave * 16 + brow) * HDIM + k0 + bsub * 8],
              &As[wave * 512]);
        for (int c = 0; c < jcount; ++c) {
            const int chunk = jstart + c;
            GLD16(bk + (size_t)chunk * 512, &Bs[chunk * 512]);
        }
        __syncthreads();

        bf16x8 af[4];
#pragma unroll
        for (int i = 0; i < 4; i++)
            af[i] = *(const bf16x8*)&As[(i * 16 + ln15) * 32 + quad * 8];

#define KSTEP(JC)                                                               \
        _Pragma("unroll") for (int j = 0; j < (JC); ++j) {                      \
            bf16x8 bfr = *(const bf16x8*)&Bs[((jstart + j) * 16 + ln15) * 32 + quad * 8]; \
            _Pragma("unroll") for (int i = 0; i < 4; ++i)                       \
                acc[i][j] = __builtin_amdgcn_mfma_f32_16x16x32_bf16(af[i], bfr, acc[i][j], 0, 0, 0); \
        }
        if (wave == 3) { KSTEP(5) } else { KSTEP(4) }
#undef KSTEP
    }

    // ---- phase 1: s = log2e*tanh(acc+bias) -> netS [row][sp][24] bf16 ----
    __syncthreads();
#define EPI1(JC)                                                                \
    _Pragma("unroll") for (int j = 0; j < (JC); ++j) {                          \
        const int col_l = (jstart + j) * 16 + ln15;                             \
        const int spc   = (col_l * 241) >> 12;   /* col_l/17, col_l<272 */      \
        const int cc    = col_l - spc * 17;                                     \
        const int basej = spc * 24 + cc;                                        \
        const float bias2L = b2[bcol + col_l] * TWOL2E;                         \
        _Pragma("unroll") for (int i = 0; i < 4; ++i)                           \
            _Pragma("unroll") for (int r = 0; r < 4; ++r) {                     \
                const int row_l = i * 16 + quad * 4 + r;                        \
                smem[row_l * 392 + basej] =                                     \
                    (short)f2bf_fast(ftanh_l2e(acc[i][j][r], bias2L));          \
            }                                                                   \
    }
    if (wave == 3) { EPI1(5) } else { EPI1(4) }
#undef EPI1
    __syncthreads();

    // ---- phase 2: spline math per (row, spline), unnormalized formulation ----
    const int sp = tid & 15;
    const int r0 = tid >> 4;
    const int sglob = blockIdx.x * 16 + sp;
    for (int t = 0; t < 4; ++t) {
        const int row_l = t * 16 + r0;
        const int row = bm + row_l;
        const int base2 = row_l * 392 + sp * 24;
        bf16x8 p0 = *(const bf16x8*)&smem[base2];
        bf16x8 p1 = *(const bf16x8*)&smem[base2 + 8];
        const short p2 = smem[base2 + 16];

        float s[17];
#pragma unroll
        for (int c = 0; c < 8; c++) s[c] = bf2f((unsigned short)p0[c]);
#pragma unroll
        for (int c = 0; c < 8; c++) s[8 + c] = bf2f((unsigned short)p1[c]);
        s[16] = bf2f((unsigned short)p2);

        // eh = 2^s (h part), e = 2^s (w part); |s|<1.45 so no max-subtraction
        float eh[9], e[8];
#pragma unroll
        for (int j = 0; j < 9; j++) eh[j] = EXP2F(s[j]);
#pragma unroll
        for (int c = 0; c < 8; c++) e[c]  = EXP2F(s[9 + c]);

        float cum_e[8], cum_u[8];
        cum_e[0] = e[0];
        cum_u[0] = e[0] * (eh[0] + eh[1]);
#pragma unroll
        for (int c = 1; c < 8; c++) {
            cum_e[c] = cum_e[c - 1] + e[c];
            cum_u[c] = fmaf(e[c], eh[c] + eh[c + 1], cum_u[c - 1]);
        }
        const float se = cum_e[7];
        const float su = cum_u[7];

        const float xb  = x[(size_t)row * (2 * SDIM) + SDIM + sglob];
        const float thr = xb * se;          // compare vs unnormalized knots

        float selE = e[0], selEH = eh[0], selEH1 = eh[1];
        float selCE = -EPSK * se, selCU = 0.f;
#pragma unroll
        for (int c = 1; c < 8; c++) {
            const bool tt = (cum_e[c - 1] < thr);
            selE   = tt ? e[c]         : selE;
            selEH  = tt ? eh[c]        : selEH;
            selEH1 = tt ? eh[c + 1]    : selEH1;
            selCE  = tt ? cum_e[c - 1] : selCE;
            selCU  = tt ? cum_u[c - 1] : selCU;
        }

        const float alpha = (thr - selCE) * RCPF(selE);
        const float dlt   = selEH1 - selEH;
        const float su_inv = RCPF(su);
        float p = fmaf(2.f * alpha, selE * selEH, selCU);
        p = fmaf(alpha * alpha, selE * dlt, p);
        out[(size_t)row * (2 * SDIM) + SDIM + sglob] = p * su_inv;

        const float g = fmaf(alpha, dlt, selEH) * (2.f * se * su_inv);
        float lg = LOG2F(g);
        lg += __shfl_xor(lg, 1);
        lg += __shfl_xor(lg, 2);
        lg += __shfl_xor(lg, 4);
        lg += __shfl_xor(lg, 8);
        if (sp == 0)
            atomicAdd(&out[(size_t)BROWS * (2 * SDIM) + row], -lg * LN2);
    }
}

// ---------------------------------------------------------------------------
extern "C" void kernel_launch(void* const* d_in, const int* in_sizes, int n_in,
                              void* d_out, int out_size, void* d_ws, size_t ws_size,
                              hipStream_t stream) {
    const float* x    = (const float*)d_in[0];
    const float* logd = (const float*)d_in[1];
    const float* W1   = (const float*)d_in[2];
    const float* b1   = (const float*)d_in[3];
    const float* W2   = (const float*)d_in[4];
    const float* b2   = (const float*)d_in[5];
    float* out = (float*)d_out;

    // ws layout (unchanged offsets; ~17.9 MiB)
    char* ws = (char*)d_ws;
    unsigned short* W1T = (unsigned short*)(ws + 32768);     // 512x512 bf16
    unsigned short* W2p = (unsigned short*)(ws + 557056);    // 8704x512 bf16 packed
    unsigned short* hid = (unsigned short*)(ws + 9469952);   // 8192x512 bf16

    prep_k<<<832, 256, 0, stream>>>(W2, W2p, W1, W1T, logd, out);
    gemm1_mfma<<<dim3(4, 128), 256, 0, stream>>>(x, W1T, b1, hid, out);
    gemm2_spline_mfma<<<dim3(32, 128), 256, 0, stream>>>(hid, W2p, b2, x, out);
}

// Round 6
// 244.667 us; speedup vs baseline: 13.7039x; 1.0643x over previous
//
#include <hip/hip_runtime.h>
#include <stdint.h>
#include <math.h>

// Problem constants
#define BROWS 8192
#define SDIM  512
#define HDIM  512
#define NCOL  8704          // S*(2K+1)
#define EPSK  1e-6f
#define LOG2E  1.442695041f
#define TWOL2E 2.885390082f
#define LN2    0.6931471806f

typedef __attribute__((ext_vector_type(8))) short bf16x8;   // MFMA A/B frag (4 VGPR)
typedef __attribute__((ext_vector_type(4))) short bf16x4;
typedef __attribute__((ext_vector_type(4))) float f32x4;    // MFMA C/D frag

__device__ __forceinline__ unsigned short f2bf(float f) {   // RTNE f32->bf16
    unsigned u = __float_as_uint(f);
    u += 0x7fffu + ((u >> 16) & 1u);
    return (unsigned short)(u >> 16);
}
__device__ __forceinline__ unsigned short f2bf_fast(float f) { // round-half-up (2 inst)
    return (unsigned short)((__float_as_uint(f) + 0x8000u) >> 16);
}
__device__ __forceinline__ float bf2f(unsigned short s) {
    return __uint_as_float(((unsigned)s) << 16);
}
#define EXP2F(x) __builtin_amdgcn_exp2f(x)   // v_exp_f32 (base 2)
#define LOG2F(x) __builtin_amdgcn_logf(x)    // v_log_f32 (base 2)
#define RCPF(x)  __builtin_amdgcn_rcpf(x)

// fast tanh, clamp-free: |2*log2e*x| < ~60 << 128 (bounded by sum|W|), so 2^t
// is always finite and (e-1)/(e+1) saturates correctly.
__device__ __forceinline__ float ftanh(float x) {
    float e = EXP2F(TWOL2E * x);
    return (e - 1.f) * RCPF(e + 1.f);
}
// log2e * tanh(acc + bias), bias pre-scaled by 2*log2e
__device__ __forceinline__ float ftanh_l2e(float acc, float bias2L) {
    float e = EXP2F(fmaf(acc, TWOL2E, bias2L));
    return fmaf(e, LOG2E, -LOG2E) * RCPF(e + 1.f);
}

// async global->LDS, 16B per lane; LDS dst is wave-uniform base + lane*16
#define GLD16(g, l)                                                         \
    __builtin_amdgcn_global_load_lds(                                       \
        (const __attribute__((address_space(1))) void*)(g),                 \
        (__attribute__((address_space(3))) void*)(l), 16, 0, 0)

// ---------------------------------------------------------------------------
// PREP (one kernel, 832 blocks):
//  [0,544)   : pack W2 -> W2p image [colblk(32)][kk(16)][chunk(17)][r16][e32]
//  [544,800) : transpose W1 -> W1T bf16 (k-contiguous)
//  [800,832) : out tail init: out[B*1024 + b] = logd[b]
// ---------------------------------------------------------------------------
__global__ __launch_bounds__(256) void prep_k(
    const float* __restrict__ W2, unsigned short* __restrict__ W2p,
    const float* __restrict__ W1, unsigned short* __restrict__ W1T,
    const float* __restrict__ logd, float* __restrict__ out)
{
    __shared__ float tile[32 * 33];
    const int t = threadIdx.x;
    if (blockIdx.x < 544) {
        const int ct = blockIdx.x;            // 0..543
        const int colbase = ct * 16;
        const int colblk = ct / 17;
        const int chunk  = ct - colblk * 17;
        const int k32 = t >> 3;               // 0..31
        const int c2  = (t & 7) * 2;          // 0..14
        const int r   = t >> 4;               // 0..15
        const int e2  = (t & 15) * 2;         // 0..30
        for (int kk = 0; kk < 16; ++kk) {
            float2 v = *(const float2*)&W2[(size_t)(kk * 32 + k32) * NCOL + colbase + c2];
            __syncthreads();
            tile[k32 * 17 + c2 + 0] = v.x;
            tile[k32 * 17 + c2 + 1] = v.y;
            __syncthreads();
            const size_t off = (((size_t)colblk * 16 + kk) * 17 + chunk) * 512;
            ushort2 o;
            o.x = f2bf(tile[(e2 + 0) * 17 + r]);
            o.y = f2bf(tile[(e2 + 1) * 17 + r]);
            *(ushort2*)&W2p[off + (size_t)r * 32 + e2] = o;
        }
    } else if (blockIdx.x < 800) {
        const int bt = blockIdx.x - 544;      // 0..255
        const int cb = (bt & 15) * 32;
        const int rb = (bt >> 4) * 32;
        const int ty = t >> 3, tx = (t & 7) * 4;
        float4 v = *(const float4*)&W1[(size_t)(rb + ty) * HDIM + cb + tx];
        tile[ty * 33 + tx + 0] = v.x;
        tile[ty * 33 + tx + 1] = v.y;
        tile[ty * 33 + tx + 2] = v.z;
        tile[ty * 33 + tx + 3] = v.w;
        __syncthreads();
        const int oy = t >> 3, ox = (t & 7) * 4;
        bf16x4 o;
        o[0] = (short)f2bf(tile[(ox + 0) * 33 + oy]);
        o[1] = (short)f2bf(tile[(ox + 1) * 33 + oy]);
        o[2] = (short)f2bf(tile[(ox + 2) * 33 + oy]);
        o[3] = (short)f2bf(tile[(ox + 3) * 33 + oy]);
        *(bf16x4*)&W1T[(size_t)(cb + oy) * SDIM + rb + ox] = o;
    } else {
        const int b = (blockIdx.x - 800) * 256 + t;   // 0..8191
        out[(size_t)BROWS * (2 * SDIM) + b] = logd[b];
    }
}

// ---------------------------------------------------------------------------
// GEMM1 (MFMA): hid = bf16(tanh((x_a-0.5) @ W1 + b1)); bn==0 blocks also copy
// x_a into out[:, :512]. 64x128 tile, BK=32, grid (4,128).
// ---------------------------------------------------------------------------
__global__ __launch_bounds__(256) void gemm1_mfma(
    const float* __restrict__ x,
    const unsigned short* __restrict__ W1T,   // (H,S) bf16 k-contiguous
    const float* __restrict__ b1,
    unsigned short* __restrict__ hid,         // (B,H) bf16
    float* __restrict__ out)
{
    __shared__ short As[64 * 32];
    __shared__ short Bs[128 * 32];
    const int bm   = blockIdx.y * 64;
    const int bn   = blockIdx.x * 128;
    const int tid  = threadIdx.x;
    const int lane = tid & 63;
    const int wave = tid >> 6;
    const int ln15 = lane & 15;
    const int quad = lane >> 4;
    const int wm   = (wave >> 1) * 32;
    const int wn   = (wave & 1) * 64;
    const int arow = tid >> 2, aseg = tid & 3;      // A: 64 rows x 4 segs of 8
    const int brow = lane >> 2, bsub = lane & 3;

    f32x4 acc[2][4];
#pragma unroll
    for (int i = 0; i < 2; i++)
#pragma unroll
        for (int j = 0; j < 4; j++) acc[i][j] = (f32x4){0.f, 0.f, 0.f, 0.f};

    for (int k0 = 0; k0 < SDIM; k0 += 32) {
        const float4* xq = (const float4*)&x[(size_t)(bm + arow) * (2 * SDIM) + k0 + aseg * 8];
        float4 f0 = xq[0], f1 = xq[1];
        if (blockIdx.x == 0) {                      // fused x_a -> out copy
            float* op = &out[(size_t)(bm + arow) * (2 * SDIM) + k0 + aseg * 8];
            *(float4*)op = f0;
            *(float4*)(op + 4) = f1;
        }
        __syncthreads();
#pragma unroll
        for (int c = 0; c < 2; c++) {
            const int chunk = wave * 2 + c;         // 0..7
            GLD16(&W1T[(size_t)(bn + chunk * 16 + brow) * SDIM + k0 + bsub * 8],
                  &Bs[chunk * 512]);
        }
        bf16x8 v0;
        v0[0] = (short)f2bf_fast(f0.x - 0.5f); v0[1] = (short)f2bf_fast(f0.y - 0.5f);
        v0[2] = (short)f2bf_fast(f0.z - 0.5f); v0[3] = (short)f2bf_fast(f0.w - 0.5f);
        v0[4] = (short)f2bf_fast(f1.x - 0.5f); v0[5] = (short)f2bf_fast(f1.y - 0.5f);
        v0[6] = (short)f2bf_fast(f1.z - 0.5f); v0[7] = (short)f2bf_fast(f1.w - 0.5f);
        *(bf16x8*)&As[arow * 32 + aseg * 8] = v0;
        __syncthreads();

        bf16x8 af[2], bfr[4];
#pragma unroll
        for (int i = 0; i < 2; i++)
            af[i] = *(const bf16x8*)&As[(wm + i * 16 + ln15) * 32 + quad * 8];
#pragma unroll
        for (int j = 0; j < 4; j++)
            bfr[j] = *(const bf16x8*)&Bs[(wn + j * 16 + ln15) * 32 + quad * 8];
#pragma unroll
        for (int i = 0; i < 2; i++)
#pragma unroll
            for (int j = 0; j < 4; j++)
                acc[i][j] = __builtin_amdgcn_mfma_f32_16x16x32_bf16(af[i], bfr[j], acc[i][j], 0, 0, 0);
    }

#pragma unroll
    for (int j = 0; j < 4; j++) {
        const int col = bn + wn + j * 16 + ln15;
        const float bias = b1[col];
#pragma unroll
        for (int i = 0; i < 2; i++) {
#pragma unroll
            for (int r = 0; r < 4; r++) {
                const int row = bm + wm + i * 16 + quad * 4 + r;
                hid[(size_t)row * HDIM + col] = f2bf(ftanh(acc[i][j][r] + bias));
            }
        }
    }
}

// ---------------------------------------------------------------------------
// GEMM2 (MFMA) fused with spline epilogue. BM=64 x BN=272 (16 splines).
// K-loop is DOUBLE-BUFFERED with ONE barrier per iteration: GLD16s for iter
// n+1 are issued right after the barrier, so the compiler's vmcnt(0) drain at
// the next barrier waits on loads that flew during this iter's MFMA work.
// netS: s = log2e*tanh(net), bf16, [row(64)][sp*20], row stride 328.
// ---------------------------------------------------------------------------
__global__ __launch_bounds__(256, 3) void gemm2_spline_mfma(
    const unsigned short* __restrict__ hid,   // (B,H) bf16
    const unsigned short* __restrict__ W2p,   // packed, see prep_k
    const float* __restrict__ b2,
    const float* __restrict__ x,              // x_b = cols [512,1024)
    float* __restrict__ out)                  // [B*1024 phi | B tail]
{
    __shared__ short smem[2 * 10752];         // 43008 B; dbuf staging / netS union

    const int bm   = blockIdx.y * 64;
    const int tid  = threadIdx.x;
    const int lane = tid & 63;
    const int wave = tid >> 6;
    const int ln15 = lane & 15;
    const int quad = lane >> 4;
    const int brow = lane >> 2, bsub = lane & 3;
    const int jstart = wave * 4;
    const int jcount = (wave == 3) ? 5 : 4;
    const int bcol = blockIdx.x * 272;

    f32x4 acc[4][5];
#pragma unroll
    for (int i = 0; i < 4; i++)
#pragma unroll
        for (int j = 0; j < 5; j++) acc[i][j] = (f32x4){0.f, 0.f, 0.f, 0.f};

    const unsigned short* bbase =
        W2p + ((size_t)blockIdx.x * 16) * 17 * 512 + (size_t)lane * 8;
    const unsigned short* abase =
        &hid[(size_t)(bm + wave * 16 + brow) * HDIM + bsub * 8];

    // issue staging loads for K-step n into buffer parity p
    auto issue = [&](int n, int p) {
        short* dst = smem + p * 10752;
        GLD16(abase + n * 32, &dst[wave * 512]);
        const unsigned short* bk = bbase + (size_t)n * (17 * 512);
        for (int c = 0; c < jcount; ++c) {
            const int chunk = jstart + c;
            GLD16(bk + (size_t)chunk * 512, &dst[2048 + chunk * 512]);
        }
    };

    issue(0, 0);                               // prologue
    for (int n = 0; n < 16; ++n) {
        __syncthreads();                       // drains loads(n) [vmcnt] + prior reads [lgkm]
        if (n < 15) issue(n + 1, (n + 1) & 1);
        const short* As = smem + (n & 1) * 10752;
        const short* Bs = As + 2048;

        bf16x8 af[4];
#pragma unroll
        for (int i = 0; i < 4; i++)
            af[i] = *(const bf16x8*)&As[(i * 16 + ln15) * 32 + quad * 8];

#define KSTEP(JC)                                                               \
        _Pragma("unroll") for (int j = 0; j < (JC); ++j) {                      \
            bf16x8 bfr = *(const bf16x8*)&Bs[((jstart + j) * 16 + ln15) * 32 + quad * 8]; \
            _Pragma("unroll") for (int i = 0; i < 4; ++i)                       \
                acc[i][j] = __builtin_amdgcn_mfma_f32_16x16x32_bf16(af[i], bfr, acc[i][j], 0, 0, 0); \
        }
        if (wave == 3) { KSTEP(5) } else { KSTEP(4) }
#undef KSTEP
    }

    // prefetch x_b for phase 2 (latency hidden under phase-1 tanh work)
    const int sp = tid & 15;
    const int r0 = tid >> 4;
    const int sglob = blockIdx.x * 16 + sp;
    float xbv[4];
#pragma unroll
    for (int t = 0; t < 4; ++t)
        xbv[t] = x[(size_t)(bm + t * 16 + r0) * (2 * SDIM) + SDIM + sglob];

    // ---- phase 1: s = log2e*tanh(acc+bias) -> netS [row][sp*20] bf16 ----
    __syncthreads();
#define EPI1(JC)                                                                \
    _Pragma("unroll") for (int j = 0; j < (JC); ++j) {                          \
        const int col_l = (jstart + j) * 16 + ln15;                             \
        const int spc   = (col_l * 241) >> 12;   /* col_l/17, col_l<272 */      \
        const int cc    = col_l - spc * 17;                                     \
        const int basej = spc * 20 + cc;                                        \
        const float bias2L = b2[bcol + col_l] * TWOL2E;                         \
        _Pragma("unroll") for (int i = 0; i < 4; ++i)                           \
            _Pragma("unroll") for (int r = 0; r < 4; ++r) {                     \
                const int row_l = i * 16 + quad * 4 + r;                        \
                smem[row_l * 328 + basej] =                                     \
                    (short)f2bf_fast(ftanh_l2e(acc[i][j][r], bias2L));          \
            }                                                                   \
    }
    if (wave == 3) { EPI1(5) } else { EPI1(4) }
#undef EPI1
    __syncthreads();

    // ---- phase 2: spline math per (row, spline), unnormalized formulation ----
    for (int t = 0; t < 4; ++t) {
        const int row_l = t * 16 + r0;
        const int row = bm + row_l;
        const int base2 = row_l * 328 + sp * 20;
        bf16x4 a0 = *(const bf16x4*)&smem[base2 + 0];
        bf16x4 a1 = *(const bf16x4*)&smem[base2 + 4];
        bf16x4 a2 = *(const bf16x4*)&smem[base2 + 8];
        bf16x4 a3 = *(const bf16x4*)&smem[base2 + 12];
        const short p2 = smem[base2 + 16];

        float s[17];
#pragma unroll
        for (int c = 0; c < 4; c++) {
            s[c]      = bf2f((unsigned short)a0[c]);
            s[4 + c]  = bf2f((unsigned short)a1[c]);
            s[8 + c]  = bf2f((unsigned short)a2[c]);
            s[12 + c] = bf2f((unsigned short)a3[c]);
        }
        s[16] = bf2f((unsigned short)p2);

        // eh = 2^s (h part), e = 2^s (w part); |s|<1.45 so no max-subtraction
        float eh[9], e[8];
#pragma unroll
        for (int j = 0; j < 9; j++) eh[j] = EXP2F(s[j]);
#pragma unroll
        for (int c = 0; c < 8; c++) e[c]  = EXP2F(s[9 + c]);

        float cum_e[8], cum_u[8];
        cum_e[0] = e[0];
        cum_u[0] = e[0] * (eh[0] + eh[1]);
#pragma unroll
        for (int c = 1; c < 8; c++) {
            cum_e[c] = cum_e[c - 1] + e[c];
            cum_u[c] = fmaf(e[c], eh[c] + eh[c + 1], cum_u[c - 1]);
        }
        const float se = cum_e[7];
        const float su = cum_u[7];
        const float thr = xbv[t] * se;      // compare vs unnormalized knots

        float selE = e[0], selEH = eh[0], selEH1 = eh[1];
        float selCE = -EPSK * se, selCU = 0.f;
#pragma unroll
        for (int c = 1; c < 8; c++) {
            const bool tt = (cum_e[c - 1] < thr);
            selE   = tt ? e[c]         : selE;
            selEH  = tt ? eh[c]        : selEH;
            selEH1 = tt ? eh[c + 1]    : selEH1;
            selCE  = tt ? cum_e[c - 1] : selCE;
            selCU  = tt ? cum_u[c - 1] : selCU;
        }

        const float alpha = (thr - selCE) * RCPF(selE);
        const float dlt   = selEH1 - selEH;
        const float su_inv = RCPF(su);
        float p = fmaf(2.f * alpha, selE * selEH, selCU);
        p = fmaf(alpha * alpha, selE * dlt, p);
        out[(size_t)row * (2 * SDIM) + SDIM + sglob] = p * su_inv;

        const float g = fmaf(alpha, dlt, selEH) * (2.f * se * su_inv);
        float lg = LOG2F(g);
        lg += __shfl_xor(lg, 1);
        lg += __shfl_xor(lg, 2);
        lg += __shfl_xor(lg, 4);
        lg += __shfl_xor(lg, 8);
        if (sp == 0)
            atomicAdd(&out[(size_t)BROWS * (2 * SDIM) + row], -lg * LN2);
    }
}

// ---------------------------------------------------------------------------
extern "C" void kernel_launch(void* const* d_in, const int* in_sizes, int n_in,
                              void* d_out, int out_size, void* d_ws, size_t ws_size,
                              hipStream_t stream) {
    const float* x    = (const float*)d_in[0];
    const float* logd = (const float*)d_in[1];
    const float* W1   = (const float*)d_in[2];
    const float* b1   = (const float*)d_in[3];
    const float* W2   = (const float*)d_in[4];
    const float* b2   = (const float*)d_in[5];
    float* out = (float*)d_out;

    // ws layout (~17.9 MiB)
    char* ws = (char*)d_ws;
    unsigned short* W1T = (unsigned short*)(ws + 32768);     // 512x512 bf16
    unsigned short* W2p = (unsigned short*)(ws + 557056);    // 8704x512 bf16 packed
    unsigned short* hid = (unsigned short*)(ws + 9469952);   // 8192x512 bf16

    prep_k<<<832, 256, 0, stream>>>(W2, W2p, W1, W1T, logd, out);
    gemm1_mfma<<<dim3(4, 128), 256, 0, stream>>>(x, W1T, b1, hid, out);
    gemm2_spline_mfma<<<dim3(32, 128), 256, 0, stream>>>(hid, W2p, b2, x, out);
}

// Round 7
// 241.134 us; speedup vs baseline: 13.9047x; 1.0147x over previous
//
#include <hip/hip_runtime.h>
#include <stdint.h>
#include <math.h>

// Problem constants
#define BROWS 8192
#define SDIM  512
#define HDIM  512
#define NCOL  8704          // S*(2K+1)
#define EPSK  1e-6f
#define LOG2E  1.442695041f
#define TWOL2E 2.885390082f
#define LN2    0.6931471806f

typedef __attribute__((ext_vector_type(8))) short bf16x8;   // MFMA A/B frag (4 VGPR)
typedef __attribute__((ext_vector_type(4))) short bf16x4;
typedef __attribute__((ext_vector_type(4))) float f32x4;    // MFMA C/D frag

__device__ __forceinline__ unsigned short f2bf(float f) {   // RTNE f32->bf16
    unsigned u = __float_as_uint(f);
    u += 0x7fffu + ((u >> 16) & 1u);
    return (unsigned short)(u >> 16);
}
__device__ __forceinline__ unsigned short f2bf_fast(float f) { // round-half-up (2 inst)
    return (unsigned short)((__float_as_uint(f) + 0x8000u) >> 16);
}
__device__ __forceinline__ float bf2f(unsigned short s) {
    return __uint_as_float(((unsigned)s) << 16);
}
#define EXP2F(x) __builtin_amdgcn_exp2f(x)   // v_exp_f32 (base 2)
#define LOG2F(x) __builtin_amdgcn_logf(x)    // v_log_f32 (base 2)
#define RCPF(x)  __builtin_amdgcn_rcpf(x)

// fast tanh, clamp-free: |2*log2e*x| < ~60 << 128 (bounded by sum|W|)
__device__ __forceinline__ float ftanh(float x) {
    float e = EXP2F(TWOL2E * x);
    return (e - 1.f) * RCPF(e + 1.f);
}
// log2e * tanh(acc + bias), bias pre-scaled by 2*log2e
__device__ __forceinline__ float ftanh_l2e(float acc, float bias2L) {
    float e = EXP2F(fmaf(acc, TWOL2E, bias2L));
    return fmaf(e, LOG2E, -LOG2E) * RCPF(e + 1.f);
}

// async global->LDS, 16B per lane; LDS dst is wave-uniform base + lane*16
#define GLD16(g, l)                                                         \
    __builtin_amdgcn_global_load_lds(                                       \
        (const __attribute__((address_space(1))) void*)(g),                 \
        (__attribute__((address_space(3))) void*)(l), 16, 0, 0)

// ---------------------------------------------------------------------------
// PREP (one kernel, 832 blocks):
//  [0,544)   : pack W2 -> W2p image [colblk(32)][kk(16)][chunk(17)][r16][e32]
//  [544,800) : transpose W1 -> W1T bf16 (k-contiguous)
//  [800,832) : out tail init: out[B*1024 + b] = logd[b]
// ---------------------------------------------------------------------------
__global__ __launch_bounds__(256) void prep_k(
    const float* __restrict__ W2, unsigned short* __restrict__ W2p,
    const float* __restrict__ W1, unsigned short* __restrict__ W1T,
    const float* __restrict__ logd, float* __restrict__ out)
{
    __shared__ float tile[32 * 33];
    const int t = threadIdx.x;
    if (blockIdx.x < 544) {
        const int ct = blockIdx.x;            // 0..543
        const int colbase = ct * 16;
        const int colblk = ct / 17;
        const int chunk  = ct - colblk * 17;
        const int k32 = t >> 3;               // 0..31
        const int c2  = (t & 7) * 2;          // 0..14
        const int r   = t >> 4;               // 0..15
        const int e2  = (t & 15) * 2;         // 0..30
        for (int kk = 0; kk < 16; ++kk) {
            float2 v = *(const float2*)&W2[(size_t)(kk * 32 + k32) * NCOL + colbase + c2];
            __syncthreads();
            tile[k32 * 17 + c2 + 0] = v.x;
            tile[k32 * 17 + c2 + 1] = v.y;
            __syncthreads();
            const size_t off = (((size_t)colblk * 16 + kk) * 17 + chunk) * 512;
            ushort2 o;
            o.x = f2bf(tile[(e2 + 0) * 17 + r]);
            o.y = f2bf(tile[(e2 + 1) * 17 + r]);
            *(ushort2*)&W2p[off + (size_t)r * 32 + e2] = o;
        }
    } else if (blockIdx.x < 800) {
        const int bt = blockIdx.x - 544;      // 0..255
        const int cb = (bt & 15) * 32;
        const int rb = (bt >> 4) * 32;
        const int ty = t >> 3, tx = (t & 7) * 4;
        float4 v = *(const float4*)&W1[(size_t)(rb + ty) * HDIM + cb + tx];
        tile[ty * 33 + tx + 0] = v.x;
        tile[ty * 33 + tx + 1] = v.y;
        tile[ty * 33 + tx + 2] = v.z;
        tile[ty * 33 + tx + 3] = v.w;
        __syncthreads();
        const int oy = t >> 3, ox = (t & 7) * 4;
        bf16x4 o;
        o[0] = (short)f2bf(tile[(ox + 0) * 33 + oy]);
        o[1] = (short)f2bf(tile[(ox + 1) * 33 + oy]);
        o[2] = (short)f2bf(tile[(ox + 2) * 33 + oy]);
        o[3] = (short)f2bf(tile[(ox + 3) * 33 + oy]);
        *(bf16x4*)&W1T[(size_t)(cb + oy) * SDIM + rb + ox] = o;
    } else {
        const int b = (blockIdx.x - 800) * 256 + t;   // 0..8191
        out[(size_t)BROWS * (2 * SDIM) + b] = logd[b];
    }
}

// ---------------------------------------------------------------------------
// GEMM1 (MFMA): hid = bf16(tanh((x_a-0.5) @ W1 + b1)); bn==0 blocks also copy
// x_a into out[:, :512]. 64x128 tile, BK=32, grid (4,128).
// ---------------------------------------------------------------------------
__global__ __launch_bounds__(256) void gemm1_mfma(
    const float* __restrict__ x,
    const unsigned short* __restrict__ W1T,   // (H,S) bf16 k-contiguous
    const float* __restrict__ b1,
    unsigned short* __restrict__ hid,         // (B,H) bf16
    float* __restrict__ out)
{
    __shared__ short As[64 * 32];
    __shared__ short Bs[128 * 32];
    const int bm   = blockIdx.y * 64;
    const int bn   = blockIdx.x * 128;
    const int tid  = threadIdx.x;
    const int lane = tid & 63;
    const int wave = tid >> 6;
    const int ln15 = lane & 15;
    const int quad = lane >> 4;
    const int wm   = (wave >> 1) * 32;
    const int wn   = (wave & 1) * 64;
    const int arow = tid >> 2, aseg = tid & 3;      // A: 64 rows x 4 segs of 8
    const int brow = lane >> 2, bsub = lane & 3;

    f32x4 acc[2][4];
#pragma unroll
    for (int i = 0; i < 2; i++)
#pragma unroll
        for (int j = 0; j < 4; j++) acc[i][j] = (f32x4){0.f, 0.f, 0.f, 0.f};

    for (int k0 = 0; k0 < SDIM; k0 += 32) {
        const float4* xq = (const float4*)&x[(size_t)(bm + arow) * (2 * SDIM) + k0 + aseg * 8];
        float4 f0 = xq[0], f1 = xq[1];
        if (blockIdx.x == 0) {                      // fused x_a -> out copy
            float* op = &out[(size_t)(bm + arow) * (2 * SDIM) + k0 + aseg * 8];
            *(float4*)op = f0;
            *(float4*)(op + 4) = f1;
        }
        __syncthreads();
#pragma unroll
        for (int c = 0; c < 2; c++) {
            const int chunk = wave * 2 + c;         // 0..7
            GLD16(&W1T[(size_t)(bn + chunk * 16 + brow) * SDIM + k0 + bsub * 8],
                  &Bs[chunk * 512]);
        }
        bf16x8 v0;
        v0[0] = (short)f2bf_fast(f0.x - 0.5f); v0[1] = (short)f2bf_fast(f0.y - 0.5f);
        v0[2] = (short)f2bf_fast(f0.z - 0.5f); v0[3] = (short)f2bf_fast(f0.w - 0.5f);
        v0[4] = (short)f2bf_fast(f1.x - 0.5f); v0[5] = (short)f2bf_fast(f1.y - 0.5f);
        v0[6] = (short)f2bf_fast(f1.z - 0.5f); v0[7] = (short)f2bf_fast(f1.w - 0.5f);
        *(bf16x8*)&As[arow * 32 + aseg * 8] = v0;
        __syncthreads();

        bf16x8 af[2], bfr[4];
#pragma unroll
        for (int i = 0; i < 2; i++)
            af[i] = *(const bf16x8*)&As[(wm + i * 16 + ln15) * 32 + quad * 8];
#pragma unroll
        for (int j = 0; j < 4; j++)
            bfr[j] = *(const bf16x8*)&Bs[(wn + j * 16 + ln15) * 32 + quad * 8];
#pragma unroll
        for (int i = 0; i < 2; i++)
#pragma unroll
            for (int j = 0; j < 4; j++)
                acc[i][j] = __builtin_amdgcn_mfma_f32_16x16x32_bf16(af[i], bfr[j], acc[i][j], 0, 0, 0);
    }

#pragma unroll
    for (int j = 0; j < 4; j++) {
        const int col = bn + wn + j * 16 + ln15;
        const float bias = b1[col];
#pragma unroll
        for (int i = 0; i < 2; i++) {
#pragma unroll
            for (int r = 0; r < 4; r++) {
                const int row = bm + wm + i * 16 + quad * 4 + r;
                hid[(size_t)row * HDIM + col] = f2bf(ftanh(acc[i][j][r] + bias));
            }
        }
    }
}

// ---------------------------------------------------------------------------
// GEMM2 (MFMA) fused with spline epilogue. BM=64 x BN=272 (16 splines).
// Grid (128 row-stripes, 32 colblks) with x FASTEST => 128 consecutive blocks
// share one 278KB W2p slice (L2-resident per XCD) instead of cycling 8.9MB.
// Dbuf K-loop, one barrier/iter. netS: C-native column-major [col272][row68]
// bf16 (s = log2e*tanh(net)); phase-1 stores are ds_write_b64 of 4 acc rows.
// ---------------------------------------------------------------------------
__global__ __launch_bounds__(256, 3) void gemm2_spline_mfma(
    const unsigned short* __restrict__ hid,   // (B,H) bf16
    const unsigned short* __restrict__ W2p,   // packed, see prep_k
    const float* __restrict__ b2,
    const float* __restrict__ x,              // x_b = cols [512,1024)
    float* __restrict__ out)                  // [B*1024 phi | B tail]
{
    __shared__ short smem[2 * 10752];         // 43008 B; dbuf staging / netS union

    const int bm     = blockIdx.x * 64;       // x = row stripe (fastest)
    const int colblk = blockIdx.y;            // y = colblock
    const int tid  = threadIdx.x;
    const int lane = tid & 63;
    const int wave = tid >> 6;
    const int ln15 = lane & 15;
    const int quad = lane >> 4;
    const int brow = lane >> 2, bsub = lane & 3;
    const int jstart = wave * 4;
    const int jcount = (wave == 3) ? 5 : 4;
    const int bcol = colblk * 272;

    f32x4 acc[4][5];
#pragma unroll
    for (int i = 0; i < 4; i++)
#pragma unroll
        for (int j = 0; j < 5; j++) acc[i][j] = (f32x4){0.f, 0.f, 0.f, 0.f};

    const unsigned short* bbase =
        W2p + ((size_t)colblk * 16) * 17 * 512 + (size_t)lane * 8;
    const unsigned short* abase =
        &hid[(size_t)(bm + wave * 16 + brow) * HDIM + bsub * 8];

    // issue staging loads for K-step n into buffer parity p
    auto issue = [&](int n, int p) {
        short* dst = smem + p * 10752;
        GLD16(abase + n * 32, &dst[wave * 512]);
        const unsigned short* bk = bbase + (size_t)n * (17 * 512);
        for (int c = 0; c < jcount; ++c) {
            const int chunk = jstart + c;
            GLD16(bk + (size_t)chunk * 512, &dst[2048 + chunk * 512]);
        }
    };

    issue(0, 0);                               // prologue
    for (int n = 0; n < 16; ++n) {
        __syncthreads();                       // drains loads(n) + prior reads
        if (n < 15) issue(n + 1, (n + 1) & 1);
        const short* As = smem + (n & 1) * 10752;
        const short* Bs = As + 2048;

        bf16x8 af[4];
#pragma unroll
        for (int i = 0; i < 4; i++)
            af[i] = *(const bf16x8*)&As[(i * 16 + ln15) * 32 + quad * 8];

#define KSTEP(JC)                                                               \
        _Pragma("unroll") for (int j = 0; j < (JC); ++j) {                      \
            bf16x8 bfr = *(const bf16x8*)&Bs[((jstart + j) * 16 + ln15) * 32 + quad * 8]; \
            _Pragma("unroll") for (int i = 0; i < 4; ++i)                       \
                acc[i][j] = __builtin_amdgcn_mfma_f32_16x16x32_bf16(af[i], bfr, acc[i][j], 0, 0, 0); \
        }
        if (wave == 3) { KSTEP(5) } else { KSTEP(4) }
#undef KSTEP
    }

    // prefetch x_b for phase 2 (latency hidden under phase-1 tanh work)
    const int sp = tid & 15;
    const int r0 = tid >> 4;
    const int sglob = colblk * 16 + sp;
    float xbv[4];
#pragma unroll
    for (int t = 0; t < 4; ++t)
        xbv[t] = x[(size_t)(bm + t * 16 + r0) * (2 * SDIM) + SDIM + sglob];

    // ---- phase 1: s = log2e*tanh(acc+bias) -> netS [col][row], stride 68 ----
    __syncthreads();
#define EPI1(JC)                                                                \
    _Pragma("unroll") for (int j = 0; j < (JC); ++j) {                          \
        const int col_l = (jstart + j) * 16 + ln15;                             \
        const float bias2L = b2[bcol + col_l] * TWOL2E;                         \
        _Pragma("unroll") for (int i = 0; i < 4; ++i) {                         \
            bf16x4 o;                                                           \
            _Pragma("unroll") for (int r = 0; r < 4; ++r)                       \
                o[r] = (short)f2bf_fast(ftanh_l2e(acc[i][j][r], bias2L));       \
            *(bf16x4*)&smem[col_l * 68 + i * 16 + quad * 4] = o;                \
        }                                                                       \
    }
    if (wave == 3) { EPI1(5) } else { EPI1(4) }
#undef EPI1
    __syncthreads();

    // ---- phase 2: spline math per (row, spline), unnormalized formulation ----
    for (int t = 0; t < 4; ++t) {
        const int row_l = t * 16 + r0;
        const int row = bm + row_l;
        const int cbase = sp * 17 * 68 + row_l;     // netS [col][row]

        float s[17];
#pragma unroll
        for (int c = 0; c < 17; c++)
            s[c] = bf2f((unsigned short)smem[cbase + c * 68]);

        // eh = 2^s (h part), e = 2^s (w part); |s|<1.45 so no max-subtraction
        float eh[9], e[8];
#pragma unroll
        for (int j = 0; j < 9; j++) eh[j] = EXP2F(s[j]);
#pragma unroll
        for (int c = 0; c < 8; c++) e[c]  = EXP2F(s[9 + c]);

        float cum_e[8], cum_u[8];
        cum_e[0] = e[0];
        cum_u[0] = e[0] * (eh[0] + eh[1]);
#pragma unroll
        for (int c = 1; c < 8; c++) {
            cum_e[c] = cum_e[c - 1] + e[c];
            cum_u[c] = fmaf(e[c], eh[c] + eh[c + 1], cum_u[c - 1]);
        }
        const float se = cum_e[7];
        const float su = cum_u[7];
        const float thr = xbv[t] * se;      // compare vs unnormalized knots

        float selE = e[0], selEH = eh[0], selEH1 = eh[1];
        float selCE = -EPSK * se, selCU = 0.f;
#pragma unroll
        for (int c = 1; c < 8; c++) {
            const bool tt = (cum_e[c - 1] < thr);
            selE   = tt ? e[c]         : selE;
            selEH  = tt ? eh[c]        : selEH;
            selEH1 = tt ? eh[c + 1]    : selEH1;
            selCE  = tt ? cum_e[c - 1] : selCE;
            selCU  = tt ? cum_u[c - 1] : selCU;
        }

        const float alpha = (thr - selCE) * RCPF(selE);
        const float dlt   = selEH1 - selEH;
        const float su_inv = RCPF(su);
        float p = fmaf(2.f * alpha, selE * selEH, selCU);
        p = fmaf(alpha * alpha, selE * dlt, p);
        out[(size_t)row * (2 * SDIM) + SDIM + sglob] = p * su_inv;

        const float g = fmaf(alpha, dlt, selEH) * (2.f * se * su_inv);
        float lg = LOG2F(g);
        lg += __shfl_xor(lg, 1);
        lg += __shfl_xor(lg, 2);
        lg += __shfl_xor(lg, 4);
        lg += __shfl_xor(lg, 8);
        if (sp == 0)
            atomicAdd(&out[(size_t)BROWS * (2 * SDIM) + row], -lg * LN2);
    }
}

// ---------------------------------------------------------------------------
extern "C" void kernel_launch(void* const* d_in, const int* in_sizes, int n_in,
                              void* d_out, int out_size, void* d_ws, size_t ws_size,
                              hipStream_t stream) {
    const float* x    = (const float*)d_in[0];
    const float* logd = (const float*)d_in[1];
    const float* W1   = (const float*)d_in[2];
    const float* b1   = (const float*)d_in[3];
    const float* W2   = (const float*)d_in[4];
    const float* b2   = (const float*)d_in[5];
    float* out = (float*)d_out;

    // ws layout (~17.9 MiB)
    char* ws = (char*)d_ws;
    unsigned short* W1T = (unsigned short*)(ws + 32768);     // 512x512 bf16
    unsigned short* W2p = (unsigned short*)(ws + 557056);    // 8704x512 bf16 packed
    unsigned short* hid = (unsigned short*)(ws + 9469952);   // 8192x512 bf16

    prep_k<<<832, 256, 0, stream>>>(W2, W2p, W1, W1T, logd, out);
    gemm1_mfma<<<dim3(4, 128), 256, 0, stream>>>(x, W1T, b1, hid, out);
    gemm2_spline_mfma<<<dim3(128, 32), 256, 0, stream>>>(hid, W2p, b2, x, out);
}